// Round 10
// baseline (428.407 us; speedup 1.0000x reference)
//
#include <hip/hip_runtime.h>

typedef unsigned short u16;
typedef __attribute__((ext_vector_type(8))) short short8;
typedef __attribute__((ext_vector_type(4))) float f32x4;
typedef __attribute__((ext_vector_type(4))) unsigned short u16x4;

#define SEQ 2048
#define DM 1024
#define NTOK 8192  // B*L
#define CH 64      // scan chunk length
#define NCH 32     // SEQ / CH

__device__ __forceinline__ float b2f(u16 u) {
  union { float f; unsigned int i; } x; x.i = ((unsigned int)u) << 16; return x.f;
}
__device__ __forceinline__ u16 f2b(float f) {
  union { float f; unsigned int i; } x; x.f = f;
  unsigned int i = x.i;
  unsigned int r = (i + 0x7FFFu + ((i >> 16) & 1u)) >> 16;
  return (u16)r;
}

__device__ __forceinline__ void gload16(const u16* g, u16* l) {
  __builtin_amdgcn_global_load_lds(
      (const __attribute__((address_space(1))) void*)g,
      (__attribute__((address_space(3))) void*)l, 16, 0, 0);
}

// fast gelu (exact erf via Abramowitz-Stegun 7.1.26, |err| < 1.5e-7)
__device__ __forceinline__ float gelu_f(float v) {
  const float z = fabsf(v) * 0.70710678118f;
  const float t = __builtin_amdgcn_rcpf(1.f + 0.3275911f * z);
  float poly = ((((1.061405429f * t - 1.453152027f) * t + 1.421413741f) * t
                 - 0.284496736f) * t + 0.254829592f) * t;
  float e = 1.f - poly * __expf(-z * z);
  float erfv = (v < 0.f) ? -e : e;
  return 0.5f * v * (1.f + erfv);
}
__device__ __forceinline__ float silu_f(float v) {
  return v * __builtin_amdgcn_rcpf(1.f + __expf(-v));
}
__device__ __forceinline__ float softplus_f(float v) {
  return fmaxf(v, 0.f) + __logf(1.f + __expf(-fabsf(v)));
}

// ---------------- weight transpose f32 (K x N) -> bf16 (N x K) ----------------
__global__ __launch_bounds__(256)
void wtrans(const float* __restrict__ in, u16* __restrict__ out,
            int K, int N, int rowOff, int ldOut)
{
  __shared__ float tile[32][33];
  const int n0 = blockIdx.x * 32;
  const int k0 = blockIdx.y * 32;
  const int tx = threadIdx.x, ty = threadIdx.y;
#pragma unroll
  for (int i = 0; i < 32; i += 8) {
    int k = k0 + ty + i, n = n0 + tx;
    tile[ty + i][tx] = (k < K && n < N) ? in[(long)k * N + n] : 0.f;
  }
  __syncthreads();
#pragma unroll
  for (int i = 0; i < 32; i += 8) {
    int n = n0 + ty + i, k = k0 + tx;
    if (n < N && k < K) out[(long)(rowOff + n) * ldOut + k] = f2b(tile[tx][ty + i]);
  }
}

// four 1024x1024 transposes in one launch (z-indexed)
__global__ __launch_bounds__(256)
void wtrans4(const float* __restrict__ s0, const float* __restrict__ s1,
             const float* __restrict__ s2, const float* __restrict__ s3,
             u16* __restrict__ d0, u16* __restrict__ d1,
             u16* __restrict__ d2, u16* __restrict__ d3)
{
  __shared__ float tile[32][33];
  const float* in; u16* out;
  switch (blockIdx.z) {
    case 0: in = s0; out = d0; break;
    case 1: in = s1; out = d1; break;
    case 2: in = s2; out = d2; break;
    default: in = s3; out = d3; break;
  }
  const int n0 = blockIdx.x * 32;
  const int k0 = blockIdx.y * 32;
  const int tx = threadIdx.x, ty = threadIdx.y;
#pragma unroll
  for (int i = 0; i < 32; i += 8)
    tile[ty + i][tx] = in[(long)(k0 + ty + i) * 1024 + n0 + tx];
  __syncthreads();
#pragma unroll
  for (int i = 0; i < 32; i += 8)
    out[(long)(n0 + ty + i) * 1024 + k0 + tx] = f2b(tile[tx][ty + i]);
}

// Bp_w/Cp_w (1024x16) -> rows [1024..1055] of WcatT (ld 1024); zero rows 1056..1151
__global__ __launch_bounds__(256)
void small_trans(const float* __restrict__ Bp, const float* __restrict__ Cp,
                 u16* __restrict__ wcatT)
{
  int t = blockIdx.x * 256 + threadIdx.x;  // 16384 threads
  int n = t >> 10, k = t & 1023;
  wcatT[(long)(1024 + n) * 1024 + k] = f2b(Bp[(long)k * 16 + n]);
  wcatT[(long)(1040 + n) * 1024 + k] = f2b(Cp[(long)k * 16 + n]);
#pragma unroll
  for (int i = 0; i < 6; ++i)
    wcatT[(long)1056 * 1024 + i * 16384 + t] = 0;
}

// ---------------- LayerNorm helpers ----------------
__device__ __forceinline__ void blockReduce2(float& a, float& b, float* s)
{
#pragma unroll
  for (int off = 32; off > 0; off >>= 1) {
    a += __shfl_xor(a, off);
    b += __shfl_xor(b, off);
  }
  const int lane = threadIdx.x & 63, wid = threadIdx.x >> 6;
  __syncthreads();
  if (lane == 0) { s[wid] = a; s[4 + wid] = b; }
  __syncthreads();
  a = s[0] + s[1] + s[2] + s[3];
  b = s[4] + s[5] + s[6] + s[7];
}

// fused LN1 -> LN2, f32 in, bf16 out (row length 1024, 256 thr x 4 elems)
__global__ __launch_bounds__(256)
void ln_ln_kernel(const float* __restrict__ x, const float* __restrict__ g1,
                  const float* __restrict__ b1, const float* __restrict__ g2,
                  const float* __restrict__ b2, u16* __restrict__ out)
{
  __shared__ float sred[8];
  const long row = blockIdx.x;
  const int t = threadIdx.x;
  const float4 xv = ((const float4*)(x + row * DM))[t];
  float s = xv.x + xv.y + xv.z + xv.w;
  float sq = xv.x * xv.x + xv.y * xv.y + xv.z * xv.z + xv.w * xv.w;
  blockReduce2(s, sq, sred);
  const float mu = s * (1.f / DM);
  const float rs = rsqrtf(sq * (1.f / DM) - mu * mu + 1e-5f);
  const float4 g1v = ((const float4*)g1)[t];
  const float4 b1v = ((const float4*)b1)[t];
  float xn[4];
  xn[0] = (xv.x - mu) * rs * g1v.x + b1v.x;
  xn[1] = (xv.y - mu) * rs * g1v.y + b1v.y;
  xn[2] = (xv.z - mu) * rs * g1v.z + b1v.z;
  xn[3] = (xv.w - mu) * rs * g1v.w + b1v.w;
  float s2 = xn[0] + xn[1] + xn[2] + xn[3];
  float sq2 = xn[0] * xn[0] + xn[1] * xn[1] + xn[2] * xn[2] + xn[3] * xn[3];
  blockReduce2(s2, sq2, sred);
  const float mu2 = s2 * (1.f / DM);
  const float rs2 = rsqrtf(sq2 * (1.f / DM) - mu2 * mu2 + 1e-5f);
  const float4 g2v = ((const float4*)g2)[t];
  const float4 b2v = ((const float4*)b2)[t];
  u16x4 o;
  o[0] = f2b((xn[0] - mu2) * rs2 * g2v.x + b2v.x);
  o[1] = f2b((xn[1] - mu2) * rs2 * g2v.y + b2v.y);
  o[2] = f2b((xn[2] - mu2) * rs2 * g2v.z + b2v.z);
  o[3] = f2b((xn[3] - mu2) * rs2 * g2v.w + b2v.w);
  *(u16x4*)(out + row * DM + t * 4) = o;
}

// single LN, bf16 in, bf16 out
__global__ __launch_bounds__(256)
void ln_bf_kernel(const u16* __restrict__ x, const float* __restrict__ g,
                  const float* __restrict__ b, u16* __restrict__ out)
{
  __shared__ float sred[8];
  const long row = blockIdx.x;
  const int t = threadIdx.x;
  const u16x4 xv4 = ((const u16x4*)(x + row * DM))[t];
  float xv[4];
#pragma unroll
  for (int j = 0; j < 4; ++j) xv[j] = b2f(xv4[j]);
  float s = xv[0] + xv[1] + xv[2] + xv[3];
  float sq = xv[0] * xv[0] + xv[1] * xv[1] + xv[2] * xv[2] + xv[3] * xv[3];
  blockReduce2(s, sq, sred);
  const float mu = s * (1.f / DM);
  const float rs = rsqrtf(sq * (1.f / DM) - mu * mu + 1e-5f);
  const float4 gv = ((const float4*)g)[t];
  const float4 bv = ((const float4*)b)[t];
  u16x4 o;
  o[0] = f2b((xv[0] - mu) * rs * gv.x + bv.x);
  o[1] = f2b((xv[1] - mu) * rs * gv.y + bv.y);
  o[2] = f2b((xv[2] - mu) * rs * gv.z + bv.z);
  o[3] = f2b((xv[3] - mu) * rs * gv.w + bv.w);
  *(u16x4*)(out + row * DM + t * 4) = o;
}

// ---------------- depthwise conv (k=3, pad 1 along L) + silu, vectorized ----------------
__global__ __launch_bounds__(256)
void conv_silu_kernel(const u16* __restrict__ x1, const float* __restrict__ w,
                      u16* __restrict__ xc)
{
  const long i8 = (long)blockIdx.x * 256 + threadIdx.x;  // NTOK*DM/8
  const long base = i8 * 8;
  const int d0 = (int)(base & (DM - 1));
  const long m = base >> 10;
  const int l = (int)(m & (SEQ - 1));
  const short8 cv = *(const short8*)(x1 + base);
  short8 lv = {}, rv = {};
  if (l > 0) lv = *(const short8*)(x1 + base - DM);
  if (l < SEQ - 1) rv = *(const short8*)(x1 + base + DM);
  short8 o;
#pragma unroll
  for (int j = 0; j < 8; ++j) {
    const int d = d0 + j;
    const float a = b2f((u16)lv[j]) * w[d * 3 + 0] + b2f((u16)cv[j]) * w[d * 3 + 1]
                  + b2f((u16)rv[j]) * w[d * 3 + 2];
    o[j] = (short)f2b(silu_f(a));
  }
  *(short8*)(xc + base) = o;
}

// ---------------- GEMM: 128xBN tile, NU K-subtiles per barrier ------------------
// MODE 2: bf16 out = gelu(acc + bias)
// MODE 4: dtBC: col<1024 -> bf16 softplus to outp (ld 1024); cols 1024..1055 -> f32
//         to outp2 (ld 32, +bias2/+bias3); col>=1056 skipped
// MODE 5: fused w1|v1 (N=2048): col<1024 -> outp (bf16, +bias); else silu -> outp2
// MODE 6: bf16 out = acc + bias + resid(f32)
// MODE 7: f32  out = acc + bias + resid(bf16)
template <int MODE, int BN, int NU>
__global__ __launch_bounds__(256)
void gemm_bt(const u16* __restrict__ A, const u16* __restrict__ BT,
             const float* __restrict__ bias, const float* __restrict__ bias2,
             const float* __restrict__ bias3, const float* __restrict__ resid,
             void* __restrict__ outp, void* __restrict__ outp2,
             int K, int ldOut, int nbx)
{
  constexpr int NF = BN / 32;            // B col fragments per wave: 4 or 2
  constexpr int ASZ = 4096 * NU;         // u16 per A buffer
  constexpr int BSUB = BN * 32;          // u16 per B subtile
  constexpr int BSZ = BSUB * NU;
  __shared__ u16 lds_a[2][ASZ];
  __shared__ u16 lds_b[2][BSZ];
  const int t = threadIdx.x;
  const int lane = t & 63;
  const int wid = t >> 6;
  const int wr = wid >> 1, wc = wid & 1;

  int bid = blockIdx.x;
  const int qch = gridDim.x >> 3;
  bid = (bid & 7) * qch + (bid >> 3);
  const long brow = (long)(bid / nbx) * 128;
  const long bcol = (long)(bid % nbx) * BN;

  f32x4 acc[4][NF] = {};

  const int srow = t >> 2;
  const int sslot = (t & 3) ^ ((t >> 3) & 3);
  const u16* aPtr = A + (brow + srow) * (long)K + sslot * 8;
  const u16* bPtr = BT + (bcol + srow) * (long)K + sslot * 8;
  u16* la = &lds_a[0][t * 8];
  u16* lb = &lds_b[0][t * 8];
  const long rowStep = 64L * K;
  const int nk = K / (32 * NU);

  const int rslot = (lane >> 4) ^ ((lane >> 1) & 3);
  const int koff = rslot * 8;
  const int arow = wr * 64 + (lane & 15);
  const int brw = (BN == 128 ? wc * 64 : wc * 32) + (lane & 15);

#define STAGE(kt, buf)                                                        \
  {                                                                           \
    _Pragma("unroll")                                                         \
    for (int su_ = 0; su_ < NU; ++su_) {                                      \
      const int k0_ = (((kt) * NU + su_) << 5);                               \
      gload16(aPtr + k0_, la + (buf) * ASZ + su_ * 4096);                     \
      gload16(aPtr + rowStep + k0_, la + (buf) * ASZ + su_ * 4096 + 2048);    \
      gload16(bPtr + k0_, lb + (buf) * BSZ + su_ * BSUB);                     \
      if constexpr (BN == 128)                                                \
        gload16(bPtr + rowStep + k0_, lb + (buf) * BSZ + su_ * BSUB + 2048);  \
    }                                                                         \
  }

  STAGE(0, 0);
  __syncthreads();
  int cur = 0;
  for (int kt = 0; kt < nk; ++kt) {
    if (kt + 1 < nk) STAGE(kt + 1, cur ^ 1);
#pragma unroll
    for (int su = 0; su < NU; ++su) {
      const u16* pa = &lds_a[cur][su * 4096];
      const u16* pb = &lds_b[cur][su * BSUB];
      short8 af[4], bfr[NF];
#pragma unroll
      for (int m = 0; m < 4; ++m)
        af[m] = *(const short8*)&pa[(arow + m * 16) * 32 + koff];
#pragma unroll
      for (int n = 0; n < NF; ++n)
        bfr[n] = *(const short8*)&pb[(brw + n * 16) * 32 + koff];
#pragma unroll
      for (int m = 0; m < 4; ++m)
#pragma unroll
        for (int n = 0; n < NF; ++n)
          acc[m][n] = __builtin_amdgcn_mfma_f32_16x16x32_bf16(af[m], bfr[n], acc[m][n], 0, 0, 0);
    }
    __syncthreads();
    cur ^= 1;
  }
#undef STAGE

  const int cc = lane & 15;
  const int r0 = (lane >> 4) * 4;
#pragma unroll
  for (int m = 0; m < 4; ++m) {
#pragma unroll
    for (int n = 0; n < NF; ++n) {
      const long col = bcol + (BN == 128 ? wc * 64 : wc * 32) + n * 16 + cc;
#pragma unroll
      for (int r = 0; r < 4; ++r) {
        const long row = brow + wr * 64 + m * 16 + r0 + r;
        float val = acc[m][n][r];
        if constexpr (MODE == 4) {
          if (col < 1024) {
            ((u16*)outp)[row * 1024 + col] = f2b(softplus_f(val + bias[col]));
          } else if (col < 1040) {
            ((float*)outp2)[row * 32 + col - 1024] = val + bias2[col - 1024];
          } else if (col < 1056) {
            ((float*)outp2)[row * 32 + col - 1024] = val + bias3[col - 1040];
          }
        } else if constexpr (MODE == 5) {
          if (col < 1024) {
            val += bias[col];
            ((u16*)outp)[row * 1024 + col] = f2b(val);
          } else {
            ((u16*)outp2)[row * 1024 + col - 1024] = f2b(silu_f(val + bias2[col - 1024]));
          }
        } else if constexpr (MODE == 6) {
          val += bias[col];
          ((u16*)outp)[row * ldOut + col] = f2b(val + resid[row * ldOut + col]);
        } else if constexpr (MODE == 7) {
          val += bias[col];
          ((float*)outp)[row * ldOut + col] = val + b2f(((const u16*)resid)[row * ldOut + col]);
        } else {  // MODE 2
          ((u16*)outp)[row * ldOut + col] = f2b(gelu_f(val + bias[col]));
        }
      }
    }
  }
}

// ---------------- chunked selective scan ----------------
// pass 1: local scan (h0=0): h_out/chunk + sum(dt) + y_local + inclusive cumdt (bf16)
__global__ __launch_bounds__(256)
void scan_pass1(const u16* __restrict__ xc, const u16* __restrict__ dtb,
                const float* __restrict__ bcb, const float* __restrict__ A_log,
                const float* __restrict__ D_p, float* __restrict__ hloc,
                float* __restrict__ sdt, u16* __restrict__ ylb, u16* __restrict__ cdb)
{
  const int bx = blockIdx.x;
  const int b = bx >> 9;
  const int ch = (bx >> 4) & 31;
  const int dBase = (bx & 15) * 64;
  const int t = threadIdx.x;
  const int dl = t >> 2;
  const int q = t & 3;
  const int d = dBase + dl;

  __shared__ float s_bc[32][32];
  __shared__ u16 s_dt[32][64];
  __shared__ u16 s_x[32][64];
  __shared__ u16 s_yl[32][64];
  __shared__ u16 s_cd[32][64];

  float Areg[4];
#pragma unroll
  for (int j = 0; j < 4; ++j) Areg[j] = -__expf(A_log[d * 16 + q * 4 + j]);
  const float Dp = D_p[d];
  float h[4] = {0.f, 0.f, 0.f, 0.f};
  float sAcc = 0.f;
  const long mBase = (long)b * SEQ + ch * CH;

  for (int c0 = 0; c0 < CH; c0 += 32) {
#pragma unroll
    for (int i = 0; i < 4; ++i) {
      int idx = i * 256 + t;
      int s = idx >> 5, j = idx & 31;
      s_bc[s][j] = bcb[(mBase + c0 + s) * 32 + j];
    }
#pragma unroll
    for (int i = 0; i < 8; ++i) {
      int idx = i * 256 + t;
      int s = idx >> 6, j = idx & 63;
      long m = mBase + c0 + s;
      s_dt[s][j] = dtb[m * DM + dBase + j];
      s_x[s][j] = xc[m * DM + dBase + j];
    }
    __syncthreads();
#pragma unroll 4
    for (int s = 0; s < 32; ++s) {
      const float dt = b2f(s_dt[s][dl]);
      const float xt = b2f(s_x[s][dl]);
      const float p = dt * xt;
      sAcc += dt;
      float y = 0.f;
#pragma unroll
      for (int j = 0; j < 4; ++j) {
        h[j] = __expf(dt * Areg[j]) * h[j] + p * s_bc[s][q * 4 + j];
        y = fmaf(h[j], s_bc[s][16 + q * 4 + j], y);
      }
      y += __shfl_xor(y, 1);
      y += __shfl_xor(y, 2);
      if (q == 0) s_yl[s][dl] = f2b(y + Dp * xt);
      if (q == 1) s_cd[s][dl] = f2b(sAcc);
    }
    __syncthreads();
#pragma unroll
    for (int i = 0; i < 8; ++i) {
      int idx = i * 256 + t;
      int s = idx >> 6, j = idx & 63;
      long m = mBase + c0 + s;
      ylb[m * DM + dBase + j] = s_yl[s][j];
      cdb[m * DM + dBase + j] = s_cd[s][j];
    }
    __syncthreads();
  }
  const long base = (((long)b * NCH + ch) * 1024 + d) * 16 + q * 4;
  float4 hv; hv.x = h[0]; hv.y = h[1]; hv.z = h[2]; hv.w = h[3];
  *(float4*)&hloc[base] = hv;
  if (q == 0) sdt[((long)b * NCH + ch) * 1024 + d] = sAcc;
}

// pass 2: sequential combine over chunks
__global__ __launch_bounds__(256)
void scan_pass2(const float* __restrict__ A_log, const float* __restrict__ sdt,
                const float* __restrict__ hloc, float* __restrict__ hin)
{
  const int tid = blockIdx.x * 256 + threadIdx.x;
  const int b = tid >> 14;
  const int dn = tid & 16383;
  const int d = dn >> 4;
  const float A = -__expf(A_log[dn]);
  float h = 0.f;
  for (int c = 0; c < NCH; ++c) {
    const long idx = (((long)b * NCH + c) << 14) + dn;
    hin[idx] = h;
    h = __expf(A * sdt[((long)b * NCH + c) * 1024 + d]) * h + hloc[idx];
  }
}

// pass 3 (parallel): yv = (y_local + sum_n C[t,n]*hin[n]*exp(A_n*cumdt)) * v
__global__ __launch_bounds__(256)
void scan_fix(const float* __restrict__ bcb, const u16* __restrict__ ylb,
              const u16* __restrict__ cdb, const u16* __restrict__ vg,
              const float* __restrict__ A_log, const float* __restrict__ hin,
              u16* __restrict__ yv)
{
  const int bx = blockIdx.x;
  const int b = bx >> 9;
  const int ch = (bx >> 4) & 31;
  const int dBase = (bx & 15) * 64;
  const int t = threadIdx.x;
  const int dl = t >> 2;
  const int q = t & 3;
  const int d = dBase + dl;

  __shared__ float s_c[32][16];
  __shared__ u16 s_cd[32][64];
  __shared__ u16 s_yl[32][64];
  __shared__ u16 s_v[32][64];
  __shared__ u16 s_o[32][64];

  float Areg[4];
#pragma unroll
  for (int j = 0; j < 4; ++j) Areg[j] = -__expf(A_log[d * 16 + q * 4 + j]);
  const float4 hv4 = *(const float4*)&hin[(((long)b * NCH + ch) * 1024 + d) * 16 + q * 4];
  const float hv[4] = {hv4.x, hv4.y, hv4.z, hv4.w};

  const long mBase = (long)b * SEQ + ch * CH;

  for (int c0 = 0; c0 < CH; c0 += 32) {
#pragma unroll
    for (int i = 0; i < 2; ++i) {
      int idx = i * 256 + t;
      int s = idx >> 4, j = idx & 15;
      s_c[s][j] = bcb[(mBase + c0 + s) * 32 + 16 + j];
    }
#pragma unroll
    for (int i = 0; i < 8; ++i) {
      int idx = i * 256 + t;
      int s = idx >> 6, j = idx & 63;
      long m = mBase + c0 + s;
      s_cd[s][j] = cdb[m * DM + dBase + j];
      s_yl[s][j] = ylb[m * DM + dBase + j];
      s_v[s][j] = vg[m * DM + dBase + j];
    }
    __syncthreads();
#pragma unroll 4
    for (int s = 0; s < 32; ++s) {
      const float cd = b2f(s_cd[s][dl]);
      float corr = 0.f;
#pragma unroll
      for (int j = 0; j < 4; ++j)
        corr = fmaf(s_c[s][q * 4 + j] * hv[j], __expf(Areg[j] * cd), corr);
      corr += __shfl_xor(corr, 1);
      corr += __shfl_xor(corr, 2);
      if (q == 0)
        s_o[s][dl] = f2b((b2f(s_yl[s][dl]) + corr) * b2f(s_v[s][dl]));
    }
    __syncthreads();
#pragma unroll
    for (int i = 0; i < 8; ++i) {
      int idx = i * 256 + t;
      int s = idx >> 6, j = idx & 63;
      yv[(mBase + c0 + s) * DM + dBase + j] = s_o[s][j];
    }
    __syncthreads();
  }
}

extern "C" void kernel_launch(void* const* d_in, const int* in_sizes, int n_in,
                              void* d_out, int out_size, void* d_ws, size_t ws_size,
                              hipStream_t stream)
{
  (void)in_sizes; (void)n_in; (void)out_size; (void)ws_size;
  const float* x      = (const float*)d_in[0];
  const float* ln1_g  = (const float*)d_in[1];
  const float* ln1_b  = (const float*)d_in[2];
  const float* ln_g   = (const float*)d_in[3];
  const float* ln_b   = (const float*)d_in[4];
  const float* w1_w   = (const float*)d_in[5];
  const float* w1_b   = (const float*)d_in[6];
  const float* v1_w   = (const float*)d_in[7];
  const float* v1_b   = (const float*)d_in[8];
  const float* w2_w   = (const float*)d_in[9];
  const float* w2_b   = (const float*)d_in[10];
  const float* conv_w = (const float*)d_in[11];
  const float* dt_w   = (const float*)d_in[12];
  const float* dt_b   = (const float*)d_in[13];
  const float* Bp_w   = (const float*)d_in[14];
  const float* Bp_b   = (const float*)d_in[15];
  const float* Cp_w   = (const float*)d_in[16];
  const float* Cp_b   = (const float*)d_in[17];
  const float* A_log  = (const float*)d_in[18];
  const float* D_p    = (const float*)d_in[19];
  const float* ln2_g  = (const float*)d_in[20];
  const float* ln2_b  = (const float*)d_in[21];
  const float* ff1_w  = (const float*)d_in[22];
  const float* ff1_b  = (const float*)d_in[23];
  const float* ff2_w  = (const float*)d_in[24];
  const float* ff2_b  = (const float*)d_in[25];

  char* ws = (char*)d_ws;
  size_t cur = 0;
  auto alloc = [&](size_t bytes) -> void* {
    void* p = ws + cur;
    cur = (cur + bytes + 255) & ~(size_t)255;
    return p;
  };

  u16* wv1T  = (u16*)alloc((size_t)2048 * 1024 * 2);   // [w1T ; v1T]
  u16* w2T   = (u16*)alloc((size_t)1024 * 1024 * 2);
  u16* wcatT = (u16*)alloc((size_t)1152 * 1024 * 2);
  u16* ff1T  = (u16*)alloc((size_t)3072 * 1024 * 2);
  u16* ff2T  = (u16*)alloc((size_t)1024 * 3072 * 2);
  u16* xm    = (u16*)alloc((size_t)NTOK * DM * 2);
  u16* x1b   = (u16*)alloc((size_t)NTOK * DM * 2);
  u16* vb    = (u16*)alloc((size_t)NTOK * DM * 2);     // 16 MB
  u16* xcb   = (u16*)alloc((size_t)NTOK * DM * 2);     // 16 MB (contiguous after vb)
  u16* dtb   = (u16*)alloc((size_t)NTOK * DM * 2);     // 16 MB (contiguous after xcb)
  float* bcb = (float*)alloc((size_t)NTOK * 32 * 4);   // [B|C] compact f32
  u16* x2u   = (u16*)alloc((size_t)NTOK * DM * 2);     // x2 bf16
  float* hloc = (float*)alloc((size_t)4 * NCH * 1024 * 16 * 4);  // 8 MB
  float* hin  = (float*)alloc((size_t)4 * NCH * 1024 * 16 * 4);  // 8 MB
  float* sdtb = (float*)alloc((size_t)4 * NCH * 1024 * 4);       // 512 KB
  u16* yvb  = xm;          // reuse: xm dead after fused GEMM; consumed by w2
  u16* ylb  = x1b;         // reuse: x1 dead after conv; consumed by scan_fix
  u16* xn2  = x1b;         // reuse: ylb dead before LN writes xn2
  u16* cdb  = x2u;         // reuse: consumed by scan_fix before w2 writes x2u
  u16* hb   = vb;          // reuse: vb+xcb+dtb = exactly 48 MB contiguous, all dead
                           // after scan_fix; ff1 output (8192x3072 bf16 = 48 MB)

  const dim3 tb32(32, 8);
  // weight prep
  wtrans4<<<dim3(32, 32, 4), tb32, 0, stream>>>(w1_w, v1_w, w2_w, dt_w,
                                                wv1T, wv1T + (size_t)1024 * 1024,
                                                w2T, wcatT);
  small_trans<<<64, 256, 0, stream>>>(Bp_w, Cp_w, wcatT);
  wtrans<<<dim3(96, 32), tb32, 0, stream>>>(ff1_w, ff1T, 1024, 3072, 0, 1024);
  wtrans<<<dim3(32, 96), tb32, 0, stream>>>(ff2_w, ff2T, 3072, 1024, 0, 3072);

  // LN1 -> LN2 -> xm (bf16)
  ln_ln_kernel<<<NTOK, 256, 0, stream>>>(x, ln1_g, ln1_b, ln_g, ln_b, xm);

  // fused: x1 = xm @ w1 + b ; v = silu(xm @ v1 + b)   (N=2048; BN=64 NU=2)
  gemm_bt<5, 64, 2><<<2048, 256, 0, stream>>>(xm, wv1T, w1_b, v1_b, nullptr, nullptr,
                                              x1b, vb, 1024, 1024, 32);

  // xc = silu(depthwise_conv(x1))
  conv_silu_kernel<<<(NTOK * DM) / (256 * 8), 256, 0, stream>>>(x1b, conv_w, xcb);

  // dt (bf16, softplus) + BC (compact f32): N=1088 grid (cols>=1088 all-pad skipped)
  gemm_bt<4, 64, 1><<<1088, 256, 0, stream>>>(xcb, wcatT, dt_b, Bp_b, Cp_b, nullptr,
                                              dtb, bcb, 1024, 1024, 17);

  // chunked selective scan: local scan (+ y_local, cumdt) -> combine -> parallel fix
  scan_pass1<<<2048, 256, 0, stream>>>(xcb, dtb, bcb, A_log, D_p, hloc, sdtb, ylb, cdb);
  scan_pass2<<<256, 256, 0, stream>>>(A_log, sdtb, hloc, hin);
  scan_fix<<<2048, 256, 0, stream>>>(bcb, ylb, cdb, vb, A_log, hin, yvb);

  // x2 = yv @ w2 + b + x  (bf16 out, f32 resid)
  gemm_bt<6, 64, 1><<<1024, 256, 0, stream>>>(yvb, w2T, w2_b, nullptr, nullptr, x,
                                              x2u, nullptr, 1024, 1024, 16);

  // xn2 = LN(x2) (bf16 in/out)
  ln_bf_kernel<<<NTOK, 256, 0, stream>>>(x2u, ln2_g, ln2_b, xn2);

  // h = gelu(xn2 @ ff1 + b) (bf16, ld 3072; BN=64 NU=2)
  gemm_bt<2, 64, 2><<<3072, 256, 0, stream>>>(xn2, ff1T, ff1_b, nullptr, nullptr, nullptr,
                                              hb, nullptr, 1024, 3072, 48);

  // out = h @ ff2 + b + x2  (f32 out, bf16 resid; BK=64 pipeline)
  gemm_bt<7, 128, 2><<<512, 256, 0, stream>>>(hb, ff2T, ff2_b, nullptr, nullptr,
                                              (const float*)x2u, d_out, nullptr,
                                              3072, 1024, 8);
}

// Round 11
// 418.976 us; speedup vs baseline: 1.0225x; 1.0225x over previous
//
#include <hip/hip_runtime.h>

typedef unsigned short u16;
typedef __attribute__((ext_vector_type(8))) short short8;
typedef __attribute__((ext_vector_type(4))) float f32x4;
typedef __attribute__((ext_vector_type(4))) unsigned short u16x4;

#define SEQ 2048
#define DM 1024
#define NTOK 8192  // B*L
#define CH 64      // scan chunk length
#define NCH 32     // SEQ / CH

__device__ __forceinline__ float b2f(u16 u) {
  union { float f; unsigned int i; } x; x.i = ((unsigned int)u) << 16; return x.f;
}
__device__ __forceinline__ u16 f2b(float f) {
  union { float f; unsigned int i; } x; x.f = f;
  unsigned int i = x.i;
  unsigned int r = (i + 0x7FFFu + ((i >> 16) & 1u)) >> 16;
  return (u16)r;
}

__device__ __forceinline__ void gload16(const u16* g, u16* l) {
  __builtin_amdgcn_global_load_lds(
      (const __attribute__((address_space(1))) void*)g,
      (__attribute__((address_space(3))) void*)l, 16, 0, 0);
}

// fast gelu (exact erf via Abramowitz-Stegun 7.1.26, |err| < 1.5e-7)
__device__ __forceinline__ float gelu_f(float v) {
  const float z = fabsf(v) * 0.70710678118f;
  const float t = __builtin_amdgcn_rcpf(1.f + 0.3275911f * z);
  float poly = ((((1.061405429f * t - 1.453152027f) * t + 1.421413741f) * t
                 - 0.284496736f) * t + 0.254829592f) * t;
  float e = 1.f - poly * __expf(-z * z);
  float erfv = (v < 0.f) ? -e : e;
  return 0.5f * v * (1.f + erfv);
}
__device__ __forceinline__ float silu_f(float v) {
  return v * __builtin_amdgcn_rcpf(1.f + __expf(-v));
}
__device__ __forceinline__ float softplus_f(float v) {
  return fmaxf(v, 0.f) + __logf(1.f + __expf(-fabsf(v)));
}

// ---------------- weight transpose f32 (K x N) -> bf16 (N x K) ----------------
__global__ __launch_bounds__(256)
void wtrans(const float* __restrict__ in, u16* __restrict__ out,
            int K, int N, int rowOff, int ldOut)
{
  __shared__ float tile[32][33];
  const int n0 = blockIdx.x * 32;
  const int k0 = blockIdx.y * 32;
  const int tx = threadIdx.x, ty = threadIdx.y;
#pragma unroll
  for (int i = 0; i < 32; i += 8) {
    int k = k0 + ty + i, n = n0 + tx;
    tile[ty + i][tx] = (k < K && n < N) ? in[(long)k * N + n] : 0.f;
  }
  __syncthreads();
#pragma unroll
  for (int i = 0; i < 32; i += 8) {
    int n = n0 + ty + i, k = k0 + tx;
    if (n < N && k < K) out[(long)(rowOff + n) * ldOut + k] = f2b(tile[tx][ty + i]);
  }
}

// four 1024x1024 transposes in one launch (z-indexed)
__global__ __launch_bounds__(256)
void wtrans4(const float* __restrict__ s0, const float* __restrict__ s1,
             const float* __restrict__ s2, const float* __restrict__ s3,
             u16* __restrict__ d0, u16* __restrict__ d1,
             u16* __restrict__ d2, u16* __restrict__ d3)
{
  __shared__ float tile[32][33];
  const float* in; u16* out;
  switch (blockIdx.z) {
    case 0: in = s0; out = d0; break;
    case 1: in = s1; out = d1; break;
    case 2: in = s2; out = d2; break;
    default: in = s3; out = d3; break;
  }
  const int n0 = blockIdx.x * 32;
  const int k0 = blockIdx.y * 32;
  const int tx = threadIdx.x, ty = threadIdx.y;
#pragma unroll
  for (int i = 0; i < 32; i += 8)
    tile[ty + i][tx] = in[(long)(k0 + ty + i) * 1024 + n0 + tx];
  __syncthreads();
#pragma unroll
  for (int i = 0; i < 32; i += 8)
    out[(long)(n0 + ty + i) * 1024 + k0 + tx] = f2b(tile[tx][ty + i]);
}

// Bp_w/Cp_w (1024x16) -> rows [1024..1055] of WcatT (ld 1024); zero rows 1056..1151
__global__ __launch_bounds__(256)
void small_trans(const float* __restrict__ Bp, const float* __restrict__ Cp,
                 u16* __restrict__ wcatT)
{
  int t = blockIdx.x * 256 + threadIdx.x;  // 16384 threads
  int n = t >> 10, k = t & 1023;
  wcatT[(long)(1024 + n) * 1024 + k] = f2b(Bp[(long)k * 16 + n]);
  wcatT[(long)(1040 + n) * 1024 + k] = f2b(Cp[(long)k * 16 + n]);
#pragma unroll
  for (int i = 0; i < 6; ++i)
    wcatT[(long)1056 * 1024 + i * 16384 + t] = 0;
}

// ---------------- LayerNorm helpers ----------------
__device__ __forceinline__ void blockReduce2(float& a, float& b, float* s)
{
#pragma unroll
  for (int off = 32; off > 0; off >>= 1) {
    a += __shfl_xor(a, off);
    b += __shfl_xor(b, off);
  }
  const int lane = threadIdx.x & 63, wid = threadIdx.x >> 6;
  __syncthreads();
  if (lane == 0) { s[wid] = a; s[4 + wid] = b; }
  __syncthreads();
  a = s[0] + s[1] + s[2] + s[3];
  b = s[4] + s[5] + s[6] + s[7];
}

// fused LN1 -> LN2, f32 in, bf16 out (row length 1024, 256 thr x 4 elems)
__global__ __launch_bounds__(256)
void ln_ln_kernel(const float* __restrict__ x, const float* __restrict__ g1,
                  const float* __restrict__ b1, const float* __restrict__ g2,
                  const float* __restrict__ b2, u16* __restrict__ out)
{
  __shared__ float sred[8];
  const long row = blockIdx.x;
  const int t = threadIdx.x;
  const float4 xv = ((const float4*)(x + row * DM))[t];
  float s = xv.x + xv.y + xv.z + xv.w;
  float sq = xv.x * xv.x + xv.y * xv.y + xv.z * xv.z + xv.w * xv.w;
  blockReduce2(s, sq, sred);
  const float mu = s * (1.f / DM);
  const float rs = rsqrtf(sq * (1.f / DM) - mu * mu + 1e-5f);
  const float4 g1v = ((const float4*)g1)[t];
  const float4 b1v = ((const float4*)b1)[t];
  float xn[4];
  xn[0] = (xv.x - mu) * rs * g1v.x + b1v.x;
  xn[1] = (xv.y - mu) * rs * g1v.y + b1v.y;
  xn[2] = (xv.z - mu) * rs * g1v.z + b1v.z;
  xn[3] = (xv.w - mu) * rs * g1v.w + b1v.w;
  float s2 = xn[0] + xn[1] + xn[2] + xn[3];
  float sq2 = xn[0] * xn[0] + xn[1] * xn[1] + xn[2] * xn[2] + xn[3] * xn[3];
  blockReduce2(s2, sq2, sred);
  const float mu2 = s2 * (1.f / DM);
  const float rs2 = rsqrtf(sq2 * (1.f / DM) - mu2 * mu2 + 1e-5f);
  const float4 g2v = ((const float4*)g2)[t];
  const float4 b2v = ((const float4*)b2)[t];
  u16x4 o;
  o[0] = f2b((xn[0] - mu2) * rs2 * g2v.x + b2v.x);
  o[1] = f2b((xn[1] - mu2) * rs2 * g2v.y + b2v.y);
  o[2] = f2b((xn[2] - mu2) * rs2 * g2v.z + b2v.z);
  o[3] = f2b((xn[3] - mu2) * rs2 * g2v.w + b2v.w);
  *(u16x4*)(out + row * DM + t * 4) = o;
}

// single LN, bf16 in, bf16 out
__global__ __launch_bounds__(256)
void ln_bf_kernel(const u16* __restrict__ x, const float* __restrict__ g,
                  const float* __restrict__ b, u16* __restrict__ out)
{
  __shared__ float sred[8];
  const long row = blockIdx.x;
  const int t = threadIdx.x;
  const u16x4 xv4 = ((const u16x4*)(x + row * DM))[t];
  float xv[4];
#pragma unroll
  for (int j = 0; j < 4; ++j) xv[j] = b2f(xv4[j]);
  float s = xv[0] + xv[1] + xv[2] + xv[3];
  float sq = xv[0] * xv[0] + xv[1] * xv[1] + xv[2] * xv[2] + xv[3] * xv[3];
  blockReduce2(s, sq, sred);
  const float mu = s * (1.f / DM);
  const float rs = rsqrtf(sq * (1.f / DM) - mu * mu + 1e-5f);
  const float4 gv = ((const float4*)g)[t];
  const float4 bv = ((const float4*)b)[t];
  u16x4 o;
  o[0] = f2b((xv[0] - mu) * rs * gv.x + bv.x);
  o[1] = f2b((xv[1] - mu) * rs * gv.y + bv.y);
  o[2] = f2b((xv[2] - mu) * rs * gv.z + bv.z);
  o[3] = f2b((xv[3] - mu) * rs * gv.w + bv.w);
  *(u16x4*)(out + row * DM + t * 4) = o;
}

// ---------------- depthwise conv (k=3, pad 1 along L) + silu, vectorized ----------------
__global__ __launch_bounds__(256)
void conv_silu_kernel(const u16* __restrict__ x1, const float* __restrict__ w,
                      u16* __restrict__ xc)
{
  const long i8 = (long)blockIdx.x * 256 + threadIdx.x;  // NTOK*DM/8
  const long base = i8 * 8;
  const int d0 = (int)(base & (DM - 1));
  const long m = base >> 10;
  const int l = (int)(m & (SEQ - 1));
  const short8 cv = *(const short8*)(x1 + base);
  short8 lv = {}, rv = {};
  if (l > 0) lv = *(const short8*)(x1 + base - DM);
  if (l < SEQ - 1) rv = *(const short8*)(x1 + base + DM);
  short8 o;
#pragma unroll
  for (int j = 0; j < 8; ++j) {
    const int d = d0 + j;
    const float a = b2f((u16)lv[j]) * w[d * 3 + 0] + b2f((u16)cv[j]) * w[d * 3 + 1]
                  + b2f((u16)rv[j]) * w[d * 3 + 2];
    o[j] = (short)f2b(silu_f(a));
  }
  *(short8*)(xc + base) = o;
}

// ---------------- GEMM: 128xBN tile, NU K-subtiles per barrier ------------------
// MODE 2: bf16 out = gelu(acc + bias)
// MODE 4: dtBC: col<1024 -> bf16 softplus to outp (ld 1024); cols 1024..1055 -> f32
//         to outp2 (ld 32, +bias2/+bias3); col>=1056 skipped
// MODE 5: fused w1|v1 (N=2048): col<1024 -> outp (bf16, +bias); else silu -> outp2
// MODE 6: bf16 out = acc + bias + resid(f32)
// MODE 7: f32  out = acc + bias + resid(bf16)
template <int MODE, int BN, int NU>
__global__ __launch_bounds__(256)
void gemm_bt(const u16* __restrict__ A, const u16* __restrict__ BT,
             const float* __restrict__ bias, const float* __restrict__ bias2,
             const float* __restrict__ bias3, const float* __restrict__ resid,
             void* __restrict__ outp, void* __restrict__ outp2,
             int K, int ldOut, int nbx)
{
  constexpr int NF = BN / 32;            // B col fragments per wave: 4 or 2
  constexpr int ASZ = 4096 * NU;         // u16 per A buffer
  constexpr int BSUB = BN * 32;          // u16 per B subtile
  constexpr int BSZ = BSUB * NU;
  __shared__ u16 lds_a[2][ASZ];
  __shared__ u16 lds_b[2][BSZ];
  const int t = threadIdx.x;
  const int lane = t & 63;
  const int wid = t >> 6;
  const int wr = wid >> 1, wc = wid & 1;

  int bid = blockIdx.x;
  const int qch = gridDim.x >> 3;
  bid = (bid & 7) * qch + (bid >> 3);
  const long brow = (long)(bid / nbx) * 128;
  const long bcol = (long)(bid % nbx) * BN;

  f32x4 acc[4][NF] = {};

  const int srow = t >> 2;
  const int sslot = (t & 3) ^ ((t >> 3) & 3);
  const u16* aPtr = A + (brow + srow) * (long)K + sslot * 8;
  const u16* bPtr = BT + (bcol + srow) * (long)K + sslot * 8;
  u16* la = &lds_a[0][t * 8];
  u16* lb = &lds_b[0][t * 8];
  const long rowStep = 64L * K;
  const int nk = K / (32 * NU);

  const int rslot = (lane >> 4) ^ ((lane >> 1) & 3);
  const int koff = rslot * 8;
  const int arow = wr * 64 + (lane & 15);
  const int brw = (BN == 128 ? wc * 64 : wc * 32) + (lane & 15);

#define STAGE(kt, buf)                                                        \
  {                                                                           \
    _Pragma("unroll")                                                         \
    for (int su_ = 0; su_ < NU; ++su_) {                                      \
      const int k0_ = (((kt) * NU + su_) << 5);                               \
      gload16(aPtr + k0_, la + (buf) * ASZ + su_ * 4096);                     \
      gload16(aPtr + rowStep + k0_, la + (buf) * ASZ + su_ * 4096 + 2048);    \
      gload16(bPtr + k0_, lb + (buf) * BSZ + su_ * BSUB);                     \
      if constexpr (BN == 128)                                                \
        gload16(bPtr + rowStep + k0_, lb + (buf) * BSZ + su_ * BSUB + 2048);  \
    }                                                                         \
  }

  STAGE(0, 0);
  __syncthreads();
  int cur = 0;
  for (int kt = 0; kt < nk; ++kt) {
    if (kt + 1 < nk) STAGE(kt + 1, cur ^ 1);
#pragma unroll
    for (int su = 0; su < NU; ++su) {
      const u16* pa = &lds_a[cur][su * 4096];
      const u16* pb = &lds_b[cur][su * BSUB];
      short8 af[4], bfr[NF];
#pragma unroll
      for (int m = 0; m < 4; ++m)
        af[m] = *(const short8*)&pa[(arow + m * 16) * 32 + koff];
#pragma unroll
      for (int n = 0; n < NF; ++n)
        bfr[n] = *(const short8*)&pb[(brw + n * 16) * 32 + koff];
#pragma unroll
      for (int m = 0; m < 4; ++m)
#pragma unroll
        for (int n = 0; n < NF; ++n)
          acc[m][n] = __builtin_amdgcn_mfma_f32_16x16x32_bf16(af[m], bfr[n], acc[m][n], 0, 0, 0);
    }
    __syncthreads();
    cur ^= 1;
  }
#undef STAGE

  const int cc = lane & 15;
  const int r0 = (lane >> 4) * 4;
#pragma unroll
  for (int m = 0; m < 4; ++m) {
#pragma unroll
    for (int n = 0; n < NF; ++n) {
      const long col = bcol + (BN == 128 ? wc * 64 : wc * 32) + n * 16 + cc;
#pragma unroll
      for (int r = 0; r < 4; ++r) {
        const long row = brow + wr * 64 + m * 16 + r0 + r;
        float val = acc[m][n][r];
        if constexpr (MODE == 4) {
          if (col < 1024) {
            ((u16*)outp)[row * 1024 + col] = f2b(softplus_f(val + bias[col]));
          } else if (col < 1040) {
            ((float*)outp2)[row * 32 + col - 1024] = val + bias2[col - 1024];
          } else if (col < 1056) {
            ((float*)outp2)[row * 32 + col - 1024] = val + bias3[col - 1040];
          }
        } else if constexpr (MODE == 5) {
          if (col < 1024) {
            val += bias[col];
            ((u16*)outp)[row * 1024 + col] = f2b(val);
          } else {
            ((u16*)outp2)[row * 1024 + col - 1024] = f2b(silu_f(val + bias2[col - 1024]));
          }
        } else if constexpr (MODE == 6) {
          val += bias[col];
          ((u16*)outp)[row * ldOut + col] = f2b(val + resid[row * ldOut + col]);
        } else if constexpr (MODE == 7) {
          val += bias[col];
          ((float*)outp)[row * ldOut + col] = val + b2f(((const u16*)resid)[row * ldOut + col]);
        } else {  // MODE 2
          ((u16*)outp)[row * ldOut + col] = f2b(gelu_f(val + bias[col]));
        }
      }
    }
  }
}

// ---------------- chunked selective scan ----------------
// pass 1: local scan (h0=0): h_out/chunk + sum(dt) + y_local + inclusive cumdt (bf16)
__global__ __launch_bounds__(256)
void scan_pass1(const u16* __restrict__ xc, const u16* __restrict__ dtb,
                const float* __restrict__ bcb, const float* __restrict__ A_log,
                const float* __restrict__ D_p, float* __restrict__ hloc,
                float* __restrict__ sdt, u16* __restrict__ ylb, u16* __restrict__ cdb)
{
  const int bx = blockIdx.x;
  const int b = bx >> 9;
  const int ch = (bx >> 4) & 31;
  const int dBase = (bx & 15) * 64;
  const int t = threadIdx.x;
  const int dl = t >> 2;
  const int q = t & 3;
  const int d = dBase + dl;

  __shared__ float s_bc[32][32];
  __shared__ u16 s_dt[32][64];
  __shared__ u16 s_x[32][64];
  __shared__ u16 s_yl[32][64];
  __shared__ u16 s_cd[32][64];

  float Areg[4];
#pragma unroll
  for (int j = 0; j < 4; ++j) Areg[j] = -__expf(A_log[d * 16 + q * 4 + j]);
  const float Dp = D_p[d];
  float h[4] = {0.f, 0.f, 0.f, 0.f};
  float sAcc = 0.f;
  const long mBase = (long)b * SEQ + ch * CH;

  for (int c0 = 0; c0 < CH; c0 += 32) {
#pragma unroll
    for (int i = 0; i < 4; ++i) {
      int idx = i * 256 + t;
      int s = idx >> 5, j = idx & 31;
      s_bc[s][j] = bcb[(mBase + c0 + s) * 32 + j];
    }
#pragma unroll
    for (int i = 0; i < 8; ++i) {
      int idx = i * 256 + t;
      int s = idx >> 6, j = idx & 63;
      long m = mBase + c0 + s;
      s_dt[s][j] = dtb[m * DM + dBase + j];
      s_x[s][j] = xc[m * DM + dBase + j];
    }
    __syncthreads();
#pragma unroll 4
    for (int s = 0; s < 32; ++s) {
      const float dt = b2f(s_dt[s][dl]);
      const float xt = b2f(s_x[s][dl]);
      const float p = dt * xt;
      sAcc += dt;
      float y = 0.f;
#pragma unroll
      for (int j = 0; j < 4; ++j) {
        h[j] = __expf(dt * Areg[j]) * h[j] + p * s_bc[s][q * 4 + j];
        y = fmaf(h[j], s_bc[s][16 + q * 4 + j], y);
      }
      y += __shfl_xor(y, 1);
      y += __shfl_xor(y, 2);
      if (q == 0) s_yl[s][dl] = f2b(y + Dp * xt);
      if (q == 1) s_cd[s][dl] = f2b(sAcc);
    }
    __syncthreads();
#pragma unroll
    for (int i = 0; i < 8; ++i) {
      int idx = i * 256 + t;
      int s = idx >> 6, j = idx & 63;
      long m = mBase + c0 + s;
      ylb[m * DM + dBase + j] = s_yl[s][j];
      cdb[m * DM + dBase + j] = s_cd[s][j];
    }
    __syncthreads();
  }
  const long base = (((long)b * NCH + ch) * 1024 + d) * 16 + q * 4;
  float4 hv; hv.x = h[0]; hv.y = h[1]; hv.z = h[2]; hv.w = h[3];
  *(float4*)&hloc[base] = hv;
  if (q == 0) sdt[((long)b * NCH + ch) * 1024 + d] = sAcc;
}

// pass 2: sequential combine over chunks
__global__ __launch_bounds__(256)
void scan_pass2(const float* __restrict__ A_log, const float* __restrict__ sdt,
                const float* __restrict__ hloc, float* __restrict__ hin)
{
  const int tid = blockIdx.x * 256 + threadIdx.x;
  const int b = tid >> 14;
  const int dn = tid & 16383;
  const int d = dn >> 4;
  const float A = -__expf(A_log[dn]);
  float h = 0.f;
  for (int c = 0; c < NCH; ++c) {
    const long idx = (((long)b * NCH + c) << 14) + dn;
    hin[idx] = h;
    h = __expf(A * sdt[((long)b * NCH + c) * 1024 + d]) * h + hloc[idx];
  }
}

// pass 3 (parallel): yv = (y_local + sum_n C[t,n]*hin[n]*exp(A_n*cumdt)) * v
__global__ __launch_bounds__(256)
void scan_fix(const float* __restrict__ bcb, const u16* __restrict__ ylb,
              const u16* __restrict__ cdb, const u16* __restrict__ vg,
              const float* __restrict__ A_log, const float* __restrict__ hin,
              u16* __restrict__ yv)
{
  const int bx = blockIdx.x;
  const int b = bx >> 9;
  const int ch = (bx >> 4) & 31;
  const int dBase = (bx & 15) * 64;
  const int t = threadIdx.x;
  const int dl = t >> 2;
  const int q = t & 3;
  const int d = dBase + dl;

  __shared__ float s_c[32][16];
  __shared__ u16 s_cd[32][64];
  __shared__ u16 s_yl[32][64];
  __shared__ u16 s_v[32][64];
  __shared__ u16 s_o[32][64];

  float Areg[4];
#pragma unroll
  for (int j = 0; j < 4; ++j) Areg[j] = -__expf(A_log[d * 16 + q * 4 + j]);
  const float4 hv4 = *(const float4*)&hin[(((long)b * NCH + ch) * 1024 + d) * 16 + q * 4];
  const float hv[4] = {hv4.x, hv4.y, hv4.z, hv4.w};

  const long mBase = (long)b * SEQ + ch * CH;

  for (int c0 = 0; c0 < CH; c0 += 32) {
#pragma unroll
    for (int i = 0; i < 2; ++i) {
      int idx = i * 256 + t;
      int s = idx >> 4, j = idx & 15;
      s_c[s][j] = bcb[(mBase + c0 + s) * 32 + 16 + j];
    }
#pragma unroll
    for (int i = 0; i < 8; ++i) {
      int idx = i * 256 + t;
      int s = idx >> 6, j = idx & 63;
      long m = mBase + c0 + s;
      s_cd[s][j] = cdb[m * DM + dBase + j];
      s_yl[s][j] = ylb[m * DM + dBase + j];
      s_v[s][j] = vg[m * DM + dBase + j];
    }
    __syncthreads();
#pragma unroll 4
    for (int s = 0; s < 32; ++s) {
      const float cd = b2f(s_cd[s][dl]);
      float corr = 0.f;
#pragma unroll
      for (int j = 0; j < 4; ++j)
        corr = fmaf(s_c[s][q * 4 + j] * hv[j], __expf(Areg[j] * cd), corr);
      corr += __shfl_xor(corr, 1);
      corr += __shfl_xor(corr, 2);
      if (q == 0)
        s_o[s][dl] = f2b((b2f(s_yl[s][dl]) + corr) * b2f(s_v[s][dl]));
    }
    __syncthreads();
#pragma unroll
    for (int i = 0; i < 8; ++i) {
      int idx = i * 256 + t;
      int s = idx >> 6, j = idx & 63;
      yv[(mBase + c0 + s) * DM + dBase + j] = s_o[s][j];
    }
    __syncthreads();
  }
}

extern "C" void kernel_launch(void* const* d_in, const int* in_sizes, int n_in,
                              void* d_out, int out_size, void* d_ws, size_t ws_size,
                              hipStream_t stream)
{
  (void)in_sizes; (void)n_in; (void)out_size; (void)ws_size;
  const float* x      = (const float*)d_in[0];
  const float* ln1_g  = (const float*)d_in[1];
  const float* ln1_b  = (const float*)d_in[2];
  const float* ln_g   = (const float*)d_in[3];
  const float* ln_b   = (const float*)d_in[4];
  const float* w1_w   = (const float*)d_in[5];
  const float* w1_b   = (const float*)d_in[6];
  const float* v1_w   = (const float*)d_in[7];
  const float* v1_b   = (const float*)d_in[8];
  const float* w2_w   = (const float*)d_in[9];
  const float* w2_b   = (const float*)d_in[10];
  const float* conv_w = (const float*)d_in[11];
  const float* dt_w   = (const float*)d_in[12];
  const float* dt_b   = (const float*)d_in[13];
  const float* Bp_w   = (const float*)d_in[14];
  const float* Bp_b   = (const float*)d_in[15];
  const float* Cp_w   = (const float*)d_in[16];
  const float* Cp_b   = (const float*)d_in[17];
  const float* A_log  = (const float*)d_in[18];
  const float* D_p    = (const float*)d_in[19];
  const float* ln2_g  = (const float*)d_in[20];
  const float* ln2_b  = (const float*)d_in[21];
  const float* ff1_w  = (const float*)d_in[22];
  const float* ff1_b  = (const float*)d_in[23];
  const float* ff2_w  = (const float*)d_in[24];
  const float* ff2_b  = (const float*)d_in[25];

  char* ws = (char*)d_ws;
  size_t cur = 0;
  auto alloc = [&](size_t bytes) -> void* {
    void* p = ws + cur;
    cur = (cur + bytes + 255) & ~(size_t)255;
    return p;
  };

  u16* wv1T  = (u16*)alloc((size_t)2048 * 1024 * 2);   // [w1T ; v1T]
  u16* w2T   = (u16*)alloc((size_t)1024 * 1024 * 2);
  u16* wcatT = (u16*)alloc((size_t)1152 * 1024 * 2);
  u16* ff1T  = (u16*)alloc((size_t)3072 * 1024 * 2);
  u16* ff2T  = (u16*)alloc((size_t)1024 * 3072 * 2);
  u16* xm    = (u16*)alloc((size_t)NTOK * DM * 2);
  u16* x1b   = (u16*)alloc((size_t)NTOK * DM * 2);
  u16* vb    = (u16*)alloc((size_t)NTOK * DM * 2);     // 16 MB
  u16* xcb   = (u16*)alloc((size_t)NTOK * DM * 2);     // 16 MB (contiguous after vb)
  u16* dtb   = (u16*)alloc((size_t)NTOK * DM * 2);     // 16 MB (contiguous after xcb)
  float* bcb = (float*)alloc((size_t)NTOK * 32 * 4);   // [B|C] compact f32
  u16* x2u   = (u16*)alloc((size_t)NTOK * DM * 2);     // x2 bf16
  float* hloc = (float*)alloc((size_t)4 * NCH * 1024 * 16 * 4);  // 8 MB
  float* hin  = (float*)alloc((size_t)4 * NCH * 1024 * 16 * 4);  // 8 MB
  float* sdtb = (float*)alloc((size_t)4 * NCH * 1024 * 4);       // 512 KB
  u16* yvb  = xm;          // reuse: xm dead after fused GEMM; consumed by w2
  u16* ylb  = x1b;         // reuse: x1 dead after conv; consumed by scan_fix
  u16* xn2  = x1b;         // reuse: ylb dead before LN writes xn2
  u16* cdb  = x2u;         // reuse: consumed by scan_fix before w2 writes x2u
  u16* hb   = vb;          // reuse: vb+xcb+dtb = exactly 48 MB contiguous, all dead
                           // after scan_fix; ff1 output (8192x3072 bf16 = 48 MB)

  const dim3 tb32(32, 8);
  // weight prep
  wtrans4<<<dim3(32, 32, 4), tb32, 0, stream>>>(w1_w, v1_w, w2_w, dt_w,
                                                wv1T, wv1T + (size_t)1024 * 1024,
                                                w2T, wcatT);
  small_trans<<<64, 256, 0, stream>>>(Bp_w, Cp_w, wcatT);
  wtrans<<<dim3(96, 32), tb32, 0, stream>>>(ff1_w, ff1T, 1024, 3072, 0, 1024);
  wtrans<<<dim3(32, 96), tb32, 0, stream>>>(ff2_w, ff2T, 3072, 1024, 0, 3072);

  // LN1 -> LN2 -> xm (bf16)
  ln_ln_kernel<<<NTOK, 256, 0, stream>>>(x, ln1_g, ln1_b, ln_g, ln_b, xm);

  // fused: x1 = xm @ w1 + b ; v = silu(xm @ v1 + b)   (N=2048; BN=128 NU=1, R9 config)
  gemm_bt<5, 128, 1><<<1024, 256, 0, stream>>>(xm, wv1T, w1_b, v1_b, nullptr, nullptr,
                                               x1b, vb, 1024, 1024, 16);

  // xc = silu(depthwise_conv(x1))
  conv_silu_kernel<<<(NTOK * DM) / (256 * 8), 256, 0, stream>>>(x1b, conv_w, xcb);

  // dt (bf16, softplus) + BC (compact f32): N=1088 grid (cols>=1088 all-pad skipped)
  gemm_bt<4, 64, 1><<<1088, 256, 0, stream>>>(xcb, wcatT, dt_b, Bp_b, Cp_b, nullptr,
                                              dtb, bcb, 1024, 1024, 17);

  // chunked selective scan: local scan (+ y_local, cumdt) -> combine -> parallel fix
  scan_pass1<<<2048, 256, 0, stream>>>(xcb, dtb, bcb, A_log, D_p, hloc, sdtb, ylb, cdb);
  scan_pass2<<<256, 256, 0, stream>>>(A_log, sdtb, hloc, hin);
  scan_fix<<<2048, 256, 0, stream>>>(bcb, ylb, cdb, vb, A_log, hin, yvb);

  // x2 = yv @ w2 + b + x  (bf16 out, f32 resid)
  gemm_bt<6, 64, 1><<<1024, 256, 0, stream>>>(yvb, w2T, w2_b, nullptr, nullptr, x,
                                              x2u, nullptr, 1024, 1024, 16);

  // xn2 = LN(x2) (bf16 in/out)
  ln_bf_kernel<<<NTOK, 256, 0, stream>>>(x2u, ln2_g, ln2_b, xn2);

  // h = gelu(xn2 @ ff1 + b) (bf16, ld 3072; BN=128 NU=2 — ff2's proven lever)
  gemm_bt<2, 128, 2><<<1536, 256, 0, stream>>>(xn2, ff1T, ff1_b, nullptr, nullptr, nullptr,
                                               hb, nullptr, 1024, 3072, 24);

  // out = h @ ff2 + b + x2  (f32 out, bf16 resid; BK=64 pipeline)
  gemm_bt<7, 128, 2><<<512, 256, 0, stream>>>(hb, ff2T, ff2_b, nullptr, nullptr,
                                              (const float*)x2u, d_out, nullptr,
                                              3072, 1024, 8);
}

// Round 12
// 403.477 us; speedup vs baseline: 1.0618x; 1.0384x over previous
//
#include <hip/hip_runtime.h>

typedef unsigned short u16;
typedef __attribute__((ext_vector_type(8))) short short8;
typedef __attribute__((ext_vector_type(4))) float f32x4;
typedef __attribute__((ext_vector_type(4))) unsigned short u16x4;

#define SEQ 2048
#define DM 1024
#define NTOK 8192  // B*L
#define CH 64      // scan chunk length
#define NCH 32     // SEQ / CH

__device__ __forceinline__ float b2f(u16 u) {
  union { float f; unsigned int i; } x; x.i = ((unsigned int)u) << 16; return x.f;
}
__device__ __forceinline__ u16 f2b(float f) {
  union { float f; unsigned int i; } x; x.f = f;
  unsigned int i = x.i;
  unsigned int r = (i + 0x7FFFu + ((i >> 16) & 1u)) >> 16;
  return (u16)r;
}

__device__ __forceinline__ void gload16(const u16* g, u16* l) {
  __builtin_amdgcn_global_load_lds(
      (const __attribute__((address_space(1))) void*)g,
      (__attribute__((address_space(3))) void*)l, 16, 0, 0);
}

// fast gelu (exact erf via Abramowitz-Stegun 7.1.26, |err| < 1.5e-7)
__device__ __forceinline__ float gelu_f(float v) {
  const float z = fabsf(v) * 0.70710678118f;
  const float t = __builtin_amdgcn_rcpf(1.f + 0.3275911f * z);
  float poly = ((((1.061405429f * t - 1.453152027f) * t + 1.421413741f) * t
                 - 0.284496736f) * t + 0.254829592f) * t;
  float e = 1.f - poly * __expf(-z * z);
  float erfv = (v < 0.f) ? -e : e;
  return 0.5f * v * (1.f + erfv);
}
__device__ __forceinline__ float silu_f(float v) {
  return v * __builtin_amdgcn_rcpf(1.f + __expf(-v));
}
__device__ __forceinline__ float softplus_f(float v) {
  return fmaxf(v, 0.f) + __logf(1.f + __expf(-fabsf(v)));
}

// ---------------- weight transpose f32 (K x N) -> bf16 (N x K) ----------------
__global__ __launch_bounds__(256)
void wtrans(const float* __restrict__ in, u16* __restrict__ out,
            int K, int N, int rowOff, int ldOut)
{
  __shared__ float tile[32][33];
  const int n0 = blockIdx.x * 32;
  const int k0 = blockIdx.y * 32;
  const int tx = threadIdx.x, ty = threadIdx.y;
#pragma unroll
  for (int i = 0; i < 32; i += 8) {
    int k = k0 + ty + i, n = n0 + tx;
    tile[ty + i][tx] = (k < K && n < N) ? in[(long)k * N + n] : 0.f;
  }
  __syncthreads();
#pragma unroll
  for (int i = 0; i < 32; i += 8) {
    int n = n0 + ty + i, k = k0 + tx;
    if (n < N && k < K) out[(long)(rowOff + n) * ldOut + k] = f2b(tile[tx][ty + i]);
  }
}

// four 1024x1024 transposes in one launch (z-indexed)
__global__ __launch_bounds__(256)
void wtrans4(const float* __restrict__ s0, const float* __restrict__ s1,
             const float* __restrict__ s2, const float* __restrict__ s3,
             u16* __restrict__ d0, u16* __restrict__ d1,
             u16* __restrict__ d2, u16* __restrict__ d3)
{
  __shared__ float tile[32][33];
  const float* in; u16* out;
  switch (blockIdx.z) {
    case 0: in = s0; out = d0; break;
    case 1: in = s1; out = d1; break;
    case 2: in = s2; out = d2; break;
    default: in = s3; out = d3; break;
  }
  const int n0 = blockIdx.x * 32;
  const int k0 = blockIdx.y * 32;
  const int tx = threadIdx.x, ty = threadIdx.y;
#pragma unroll
  for (int i = 0; i < 32; i += 8)
    tile[ty + i][tx] = in[(long)(k0 + ty + i) * 1024 + n0 + tx];
  __syncthreads();
#pragma unroll
  for (int i = 0; i < 32; i += 8)
    out[(long)(n0 + ty + i) * 1024 + k0 + tx] = f2b(tile[tx][ty + i]);
}

// Bp_w/Cp_w (1024x16) -> rows [1024..1055] of WcatT (ld 1024); zero rows 1056..1151
__global__ __launch_bounds__(256)
void small_trans(const float* __restrict__ Bp, const float* __restrict__ Cp,
                 u16* __restrict__ wcatT)
{
  int t = blockIdx.x * 256 + threadIdx.x;  // 16384 threads
  int n = t >> 10, k = t & 1023;
  wcatT[(long)(1024 + n) * 1024 + k] = f2b(Bp[(long)k * 16 + n]);
  wcatT[(long)(1040 + n) * 1024 + k] = f2b(Cp[(long)k * 16 + n]);
#pragma unroll
  for (int i = 0; i < 6; ++i)
    wcatT[(long)1056 * 1024 + i * 16384 + t] = 0;
}

// ---------------- LayerNorm helpers ----------------
__device__ __forceinline__ void blockReduce2(float& a, float& b, float* s)
{
#pragma unroll
  for (int off = 32; off > 0; off >>= 1) {
    a += __shfl_xor(a, off);
    b += __shfl_xor(b, off);
  }
  const int lane = threadIdx.x & 63, wid = threadIdx.x >> 6;
  __syncthreads();
  if (lane == 0) { s[wid] = a; s[4 + wid] = b; }
  __syncthreads();
  a = s[0] + s[1] + s[2] + s[3];
  b = s[4] + s[5] + s[6] + s[7];
}

// fused LN1 -> LN2, f32 in, bf16 out (row length 1024, 256 thr x 4 elems)
__global__ __launch_bounds__(256)
void ln_ln_kernel(const float* __restrict__ x, const float* __restrict__ g1,
                  const float* __restrict__ b1, const float* __restrict__ g2,
                  const float* __restrict__ b2, u16* __restrict__ out)
{
  __shared__ float sred[8];
  const long row = blockIdx.x;
  const int t = threadIdx.x;
  const float4 xv = ((const float4*)(x + row * DM))[t];
  float s = xv.x + xv.y + xv.z + xv.w;
  float sq = xv.x * xv.x + xv.y * xv.y + xv.z * xv.z + xv.w * xv.w;
  blockReduce2(s, sq, sred);
  const float mu = s * (1.f / DM);
  const float rs = rsqrtf(sq * (1.f / DM) - mu * mu + 1e-5f);
  const float4 g1v = ((const float4*)g1)[t];
  const float4 b1v = ((const float4*)b1)[t];
  float xn[4];
  xn[0] = (xv.x - mu) * rs * g1v.x + b1v.x;
  xn[1] = (xv.y - mu) * rs * g1v.y + b1v.y;
  xn[2] = (xv.z - mu) * rs * g1v.z + b1v.z;
  xn[3] = (xv.w - mu) * rs * g1v.w + b1v.w;
  float s2 = xn[0] + xn[1] + xn[2] + xn[3];
  float sq2 = xn[0] * xn[0] + xn[1] * xn[1] + xn[2] * xn[2] + xn[3] * xn[3];
  blockReduce2(s2, sq2, sred);
  const float mu2 = s2 * (1.f / DM);
  const float rs2 = rsqrtf(sq2 * (1.f / DM) - mu2 * mu2 + 1e-5f);
  const float4 g2v = ((const float4*)g2)[t];
  const float4 b2v = ((const float4*)b2)[t];
  u16x4 o;
  o[0] = f2b((xn[0] - mu2) * rs2 * g2v.x + b2v.x);
  o[1] = f2b((xn[1] - mu2) * rs2 * g2v.y + b2v.y);
  o[2] = f2b((xn[2] - mu2) * rs2 * g2v.z + b2v.z);
  o[3] = f2b((xn[3] - mu2) * rs2 * g2v.w + b2v.w);
  *(u16x4*)(out + row * DM + t * 4) = o;
}

// single LN, bf16 in, bf16 out
__global__ __launch_bounds__(256)
void ln_bf_kernel(const u16* __restrict__ x, const float* __restrict__ g,
                  const float* __restrict__ b, u16* __restrict__ out)
{
  __shared__ float sred[8];
  const long row = blockIdx.x;
  const int t = threadIdx.x;
  const u16x4 xv4 = ((const u16x4*)(x + row * DM))[t];
  float xv[4];
#pragma unroll
  for (int j = 0; j < 4; ++j) xv[j] = b2f(xv4[j]);
  float s = xv[0] + xv[1] + xv[2] + xv[3];
  float sq = xv[0] * xv[0] + xv[1] * xv[1] + xv[2] * xv[2] + xv[3] * xv[3];
  blockReduce2(s, sq, sred);
  const float mu = s * (1.f / DM);
  const float rs = rsqrtf(sq * (1.f / DM) - mu * mu + 1e-5f);
  const float4 gv = ((const float4*)g)[t];
  const float4 bv = ((const float4*)b)[t];
  u16x4 o;
  o[0] = f2b((xv[0] - mu) * rs * gv.x + bv.x);
  o[1] = f2b((xv[1] - mu) * rs * gv.y + bv.y);
  o[2] = f2b((xv[2] - mu) * rs * gv.z + bv.z);
  o[3] = f2b((xv[3] - mu) * rs * gv.w + bv.w);
  *(u16x4*)(out + row * DM + t * 4) = o;
}

// ---------------- depthwise conv (k=3, pad 1 along L) + silu, vectorized ----------------
__global__ __launch_bounds__(256)
void conv_silu_kernel(const u16* __restrict__ x1, const float* __restrict__ w,
                      u16* __restrict__ xc)
{
  const long i8 = (long)blockIdx.x * 256 + threadIdx.x;  // NTOK*DM/8
  const long base = i8 * 8;
  const int d0 = (int)(base & (DM - 1));
  const long m = base >> 10;
  const int l = (int)(m & (SEQ - 1));
  const short8 cv = *(const short8*)(x1 + base);
  short8 lv = {}, rv = {};
  if (l > 0) lv = *(const short8*)(x1 + base - DM);
  if (l < SEQ - 1) rv = *(const short8*)(x1 + base + DM);
  short8 o;
#pragma unroll
  for (int j = 0; j < 8; ++j) {
    const int d = d0 + j;
    const float a = b2f((u16)lv[j]) * w[d * 3 + 0] + b2f((u16)cv[j]) * w[d * 3 + 1]
                  + b2f((u16)rv[j]) * w[d * 3 + 2];
    o[j] = (short)f2b(silu_f(a));
  }
  *(short8*)(xc + base) = o;
}

// ---------------- GEMM: (WM*64)xBN tile, NU K-subtiles per barrier, WM*128 thr ----
// WM = waves along M (2 -> 128-row tile / 256 thr; 4 -> 256-row tile / 512 thr).
// MODE 2: bf16 out = gelu(acc + bias)
// MODE 4: dtBC: col<1024 -> bf16 softplus to outp (ld 1024); cols 1024..1055 -> f32
//         to outp2 (ld 32, +bias2/+bias3); col>=1056 skipped
// MODE 5: fused w1|v1 (N=2048): col<1024 -> outp (bf16, +bias); else silu -> outp2
// MODE 6: bf16 out = acc + bias + resid(f32)
// MODE 7: f32  out = acc + bias + resid(bf16)
template <int MODE, int BN, int NU, int WM>
__global__ __launch_bounds__(WM * 128)
void gemm_bt(const u16* __restrict__ A, const u16* __restrict__ BT,
             const float* __restrict__ bias, const float* __restrict__ bias2,
             const float* __restrict__ bias3, const float* __restrict__ resid,
             void* __restrict__ outp, void* __restrict__ outp2,
             int K, int ldOut, int nbx)
{
  constexpr int T = WM * 128;            // threads
  constexpr int NF = BN / 32;            // B col fragments per wave: 4 or 2
  constexpr int ASUB = WM * 2048;        // u16 per A subtile (WM*64 rows x 32)
  constexpr int ASZ = ASUB * NU;
  constexpr int BSUB = BN * 32;          // u16 per B subtile
  constexpr int BSZ = BSUB * NU;
  constexpr int BLOADS = (BN * 4) / T;   // B gloads per thread per subtile (1 or 2)
  static_assert(BLOADS >= 1, "bad BN/WM combo");
  __shared__ u16 lds_a[2][ASZ];
  __shared__ u16 lds_b[2][BSZ];
  const int t = threadIdx.x;
  const int lane = t & 63;
  const int wid = t >> 6;
  const int wr = wid >> 1, wc = wid & 1;  // wr in 0..WM-1

  int bid = blockIdx.x;
  const int qch = gridDim.x >> 3;
  bid = (bid & 7) * qch + (bid >> 3);
  const long brow = (long)(bid / nbx) * (WM * 64);
  const long bcol = (long)(bid % nbx) * BN;

  f32x4 acc[4][NF] = {};

  const int srow = t >> 2;               // 0..T/4-1
  const int sslot = (t & 3) ^ ((t >> 3) & 3);
  const u16* aPtr = A + (brow + srow) * (long)K + sslot * 8;
  const u16* bPtr = BT + (bcol + srow) * (long)K + sslot * 8;
  u16* la = &lds_a[0][t * 8];
  u16* lb = &lds_b[0][t * 8];
  const long rowStep = (long)(T >> 2) * K;   // T/4 rows per gload pass
  const int nk = K / (32 * NU);

  const int rslot = (lane >> 4) ^ ((lane >> 1) & 3);
  const int koff = rslot * 8;
  const int arow = wr * 64 + (lane & 15);
  const int brw = (BN == 128 ? wc * 64 : wc * 32) + (lane & 15);

#define STAGE(kt, buf)                                                        \
  {                                                                           \
    _Pragma("unroll")                                                         \
    for (int su_ = 0; su_ < NU; ++su_) {                                      \
      const int k0_ = (((kt) * NU + su_) << 5);                               \
      gload16(aPtr + k0_, la + (buf) * ASZ + su_ * ASUB);                     \
      gload16(aPtr + rowStep + k0_, la + (buf) * ASZ + su_ * ASUB + T * 8);   \
      gload16(bPtr + k0_, lb + (buf) * BSZ + su_ * BSUB);                     \
      if constexpr (BLOADS == 2)                                              \
        gload16(bPtr + rowStep + k0_, lb + (buf) * BSZ + su_ * BSUB + T * 8); \
    }                                                                         \
  }

  STAGE(0, 0);
  __syncthreads();
  int cur = 0;
  for (int kt = 0; kt < nk; ++kt) {
    if (kt + 1 < nk) STAGE(kt + 1, cur ^ 1);
#pragma unroll
    for (int su = 0; su < NU; ++su) {
      const u16* pa = &lds_a[cur][su * ASUB];
      const u16* pb = &lds_b[cur][su * BSUB];
      short8 af[4], bfr[NF];
#pragma unroll
      for (int m = 0; m < 4; ++m)
        af[m] = *(const short8*)&pa[(arow + m * 16) * 32 + koff];
#pragma unroll
      for (int n = 0; n < NF; ++n)
        bfr[n] = *(const short8*)&pb[(brw + n * 16) * 32 + koff];
#pragma unroll
      for (int m = 0; m < 4; ++m)
#pragma unroll
        for (int n = 0; n < NF; ++n)
          acc[m][n] = __builtin_amdgcn_mfma_f32_16x16x32_bf16(af[m], bfr[n], acc[m][n], 0, 0, 0);
    }
    __syncthreads();
    cur ^= 1;
  }
#undef STAGE

  const int cc = lane & 15;
  const int r0 = (lane >> 4) * 4;
#pragma unroll
  for (int m = 0; m < 4; ++m) {
#pragma unroll
    for (int n = 0; n < NF; ++n) {
      const long col = bcol + (BN == 128 ? wc * 64 : wc * 32) + n * 16 + cc;
#pragma unroll
      for (int r = 0; r < 4; ++r) {
        const long row = brow + wr * 64 + m * 16 + r0 + r;
        float val = acc[m][n][r];
        if constexpr (MODE == 4) {
          if (col < 1024) {
            ((u16*)outp)[row * 1024 + col] = f2b(softplus_f(val + bias[col]));
          } else if (col < 1040) {
            ((float*)outp2)[row * 32 + col - 1024] = val + bias2[col - 1024];
          } else if (col < 1056) {
            ((float*)outp2)[row * 32 + col - 1024] = val + bias3[col - 1040];
          }
        } else if constexpr (MODE == 5) {
          if (col < 1024) {
            val += bias[col];
            ((u16*)outp)[row * 1024 + col] = f2b(val);
          } else {
            ((u16*)outp2)[row * 1024 + col - 1024] = f2b(silu_f(val + bias2[col - 1024]));
          }
        } else if constexpr (MODE == 6) {
          val += bias[col];
          ((u16*)outp)[row * ldOut + col] = f2b(val + resid[row * ldOut + col]);
        } else if constexpr (MODE == 7) {
          val += bias[col];
          ((float*)outp)[row * ldOut + col] = val + b2f(((const u16*)resid)[row * ldOut + col]);
        } else {  // MODE 2
          ((u16*)outp)[row * ldOut + col] = f2b(gelu_f(val + bias[col]));
        }
      }
    }
  }
}

// ---------------- chunked selective scan ----------------
// pass 1: local scan (h0=0): h_out/chunk + sum(dt) + y_local + inclusive cumdt (bf16)
__global__ __launch_bounds__(256)
void scan_pass1(const u16* __restrict__ xc, const u16* __restrict__ dtb,
                const float* __restrict__ bcb, const float* __restrict__ A_log,
                const float* __restrict__ D_p, float* __restrict__ hloc,
                float* __restrict__ sdt, u16* __restrict__ ylb, u16* __restrict__ cdb)
{
  const int bx = blockIdx.x;
  const int b = bx >> 9;
  const int ch = (bx >> 4) & 31;
  const int dBase = (bx & 15) * 64;
  const int t = threadIdx.x;
  const int dl = t >> 2;
  const int q = t & 3;
  const int d = dBase + dl;

  __shared__ float s_bc[32][32];
  __shared__ u16 s_dt[32][64];
  __shared__ u16 s_x[32][64];
  __shared__ u16 s_yl[32][64];
  __shared__ u16 s_cd[32][64];

  float Areg[4];
#pragma unroll
  for (int j = 0; j < 4; ++j) Areg[j] = -__expf(A_log[d * 16 + q * 4 + j]);
  const float Dp = D_p[d];
  float h[4] = {0.f, 0.f, 0.f, 0.f};
  float sAcc = 0.f;
  const long mBase = (long)b * SEQ + ch * CH;

  for (int c0 = 0; c0 < CH; c0 += 32) {
#pragma unroll
    for (int i = 0; i < 4; ++i) {
      int idx = i * 256 + t;
      int s = idx >> 5, j = idx & 31;
      s_bc[s][j] = bcb[(mBase + c0 + s) * 32 + j];
    }
#pragma unroll
    for (int i = 0; i < 8; ++i) {
      int idx = i * 256 + t;
      int s = idx >> 6, j = idx & 63;
      long m = mBase + c0 + s;
      s_dt[s][j] = dtb[m * DM + dBase + j];
      s_x[s][j] = xc[m * DM + dBase + j];
    }
    __syncthreads();
#pragma unroll 4
    for (int s = 0; s < 32; ++s) {
      const float dt = b2f(s_dt[s][dl]);
      const float xt = b2f(s_x[s][dl]);
      const float p = dt * xt;
      sAcc += dt;
      float y = 0.f;
#pragma unroll
      for (int j = 0; j < 4; ++j) {
        h[j] = __expf(dt * Areg[j]) * h[j] + p * s_bc[s][q * 4 + j];
        y = fmaf(h[j], s_bc[s][16 + q * 4 + j], y);
      }
      y += __shfl_xor(y, 1);
      y += __shfl_xor(y, 2);
      if (q == 0) s_yl[s][dl] = f2b(y + Dp * xt);
      if (q == 1) s_cd[s][dl] = f2b(sAcc);
    }
    __syncthreads();
#pragma unroll
    for (int i = 0; i < 8; ++i) {
      int idx = i * 256 + t;
      int s = idx >> 6, j = idx & 63;
      long m = mBase + c0 + s;
      ylb[m * DM + dBase + j] = s_yl[s][j];
      cdb[m * DM + dBase + j] = s_cd[s][j];
    }
    __syncthreads();
  }
  const long base = (((long)b * NCH + ch) * 1024 + d) * 16 + q * 4;
  float4 hv; hv.x = h[0]; hv.y = h[1]; hv.z = h[2]; hv.w = h[3];
  *(float4*)&hloc[base] = hv;
  if (q == 0) sdt[((long)b * NCH + ch) * 1024 + d] = sAcc;
}

// pass 2: sequential combine over chunks
__global__ __launch_bounds__(256)
void scan_pass2(const float* __restrict__ A_log, const float* __restrict__ sdt,
                const float* __restrict__ hloc, float* __restrict__ hin)
{
  const int tid = blockIdx.x * 256 + threadIdx.x;
  const int b = tid >> 14;
  const int dn = tid & 16383;
  const int d = dn >> 4;
  const float A = -__expf(A_log[dn]);
  float h = 0.f;
  for (int c = 0; c < NCH; ++c) {
    const long idx = (((long)b * NCH + c) << 14) + dn;
    hin[idx] = h;
    h = __expf(A * sdt[((long)b * NCH + c) * 1024 + d]) * h + hloc[idx];
  }
}

// pass 3 (parallel): yv = (y_local + sum_n C[t,n]*hin[n]*exp(A_n*cumdt)) * v
__global__ __launch_bounds__(256)
void scan_fix(const float* __restrict__ bcb, const u16* __restrict__ ylb,
              const u16* __restrict__ cdb, const u16* __restrict__ vg,
              const float* __restrict__ A_log, const float* __restrict__ hin,
              u16* __restrict__ yv)
{
  const int bx = blockIdx.x;
  const int b = bx >> 9;
  const int ch = (bx >> 4) & 31;
  const int dBase = (bx & 15) * 64;
  const int t = threadIdx.x;
  const int dl = t >> 2;
  const int q = t & 3;
  const int d = dBase + dl;

  __shared__ float s_c[32][16];
  __shared__ u16 s_cd[32][64];
  __shared__ u16 s_yl[32][64];
  __shared__ u16 s_v[32][64];
  __shared__ u16 s_o[32][64];

  float Areg[4];
#pragma unroll
  for (int j = 0; j < 4; ++j) Areg[j] = -__expf(A_log[d * 16 + q * 4 + j]);
  const float4 hv4 = *(const float4*)&hin[(((long)b * NCH + ch) * 1024 + d) * 16 + q * 4];
  const float hv[4] = {hv4.x, hv4.y, hv4.z, hv4.w};

  const long mBase = (long)b * SEQ + ch * CH;

  for (int c0 = 0; c0 < CH; c0 += 32) {
#pragma unroll
    for (int i = 0; i < 2; ++i) {
      int idx = i * 256 + t;
      int s = idx >> 4, j = idx & 15;
      s_c[s][j] = bcb[(mBase + c0 + s) * 32 + 16 + j];
    }
#pragma unroll
    for (int i = 0; i < 8; ++i) {
      int idx = i * 256 + t;
      int s = idx >> 6, j = idx & 63;
      long m = mBase + c0 + s;
      s_cd[s][j] = cdb[m * DM + dBase + j];
      s_yl[s][j] = ylb[m * DM + dBase + j];
      s_v[s][j] = vg[m * DM + dBase + j];
    }
    __syncthreads();
#pragma unroll 4
    for (int s = 0; s < 32; ++s) {
      const float cd = b2f(s_cd[s][dl]);
      float corr = 0.f;
#pragma unroll
      for (int j = 0; j < 4; ++j)
        corr = fmaf(s_c[s][q * 4 + j] * hv[j], __expf(Areg[j] * cd), corr);
      corr += __shfl_xor(corr, 1);
      corr += __shfl_xor(corr, 2);
      if (q == 0)
        s_o[s][dl] = f2b((b2f(s_yl[s][dl]) + corr) * b2f(s_v[s][dl]));
    }
    __syncthreads();
#pragma unroll
    for (int i = 0; i < 8; ++i) {
      int idx = i * 256 + t;
      int s = idx >> 6, j = idx & 63;
      yv[(mBase + c0 + s) * DM + dBase + j] = s_o[s][j];
    }
    __syncthreads();
  }
}

extern "C" void kernel_launch(void* const* d_in, const int* in_sizes, int n_in,
                              void* d_out, int out_size, void* d_ws, size_t ws_size,
                              hipStream_t stream)
{
  (void)in_sizes; (void)n_in; (void)out_size; (void)ws_size;
  const float* x      = (const float*)d_in[0];
  const float* ln1_g  = (const float*)d_in[1];
  const float* ln1_b  = (const float*)d_in[2];
  const float* ln_g   = (const float*)d_in[3];
  const float* ln_b   = (const float*)d_in[4];
  const float* w1_w   = (const float*)d_in[5];
  const float* w1_b   = (const float*)d_in[6];
  const float* v1_w   = (const float*)d_in[7];
  const float* v1_b   = (const float*)d_in[8];
  const float* w2_w   = (const float*)d_in[9];
  const float* w2_b   = (const float*)d_in[10];
  const float* conv_w = (const float*)d_in[11];
  const float* dt_w   = (const float*)d_in[12];
  const float* dt_b   = (const float*)d_in[13];
  const float* Bp_w   = (const float*)d_in[14];
  const float* Bp_b   = (const float*)d_in[15];
  const float* Cp_w   = (const float*)d_in[16];
  const float* Cp_b   = (const float*)d_in[17];
  const float* A_log  = (const float*)d_in[18];
  const float* D_p    = (const float*)d_in[19];
  const float* ln2_g  = (const float*)d_in[20];
  const float* ln2_b  = (const float*)d_in[21];
  const float* ff1_w  = (const float*)d_in[22];
  const float* ff1_b  = (const float*)d_in[23];
  const float* ff2_w  = (const float*)d_in[24];
  const float* ff2_b  = (const float*)d_in[25];

  char* ws = (char*)d_ws;
  size_t cur = 0;
  auto alloc = [&](size_t bytes) -> void* {
    void* p = ws + cur;
    cur = (cur + bytes + 255) & ~(size_t)255;
    return p;
  };

  u16* wv1T  = (u16*)alloc((size_t)2048 * 1024 * 2);   // [w1T ; v1T]
  u16* w2T   = (u16*)alloc((size_t)1024 * 1024 * 2);
  u16* wcatT = (u16*)alloc((size_t)1152 * 1024 * 2);
  u16* ff1T  = (u16*)alloc((size_t)3072 * 1024 * 2);
  u16* ff2T  = (u16*)alloc((size_t)1024 * 3072 * 2);
  u16* xm    = (u16*)alloc((size_t)NTOK * DM * 2);
  u16* x1b   = (u16*)alloc((size_t)NTOK * DM * 2);
  u16* vb    = (u16*)alloc((size_t)NTOK * DM * 2);     // 16 MB
  u16* xcb   = (u16*)alloc((size_t)NTOK * DM * 2);     // 16 MB (contiguous after vb)
  u16* dtb   = (u16*)alloc((size_t)NTOK * DM * 2);     // 16 MB (contiguous after xcb)
  float* bcb = (float*)alloc((size_t)NTOK * 32 * 4);   // [B|C] compact f32
  u16* x2u   = (u16*)alloc((size_t)NTOK * DM * 2);     // x2 bf16
  float* hloc = (float*)alloc((size_t)4 * NCH * 1024 * 16 * 4);  // 8 MB
  float* hin  = (float*)alloc((size_t)4 * NCH * 1024 * 16 * 4);  // 8 MB
  float* sdtb = (float*)alloc((size_t)4 * NCH * 1024 * 4);       // 512 KB
  u16* yvb  = xm;          // reuse: xm dead after fused GEMM; consumed by w2
  u16* ylb  = x1b;         // reuse: x1 dead after conv; consumed by scan_fix
  u16* xn2  = x1b;         // reuse: ylb dead before LN writes xn2
  u16* cdb  = x2u;         // reuse: consumed by scan_fix before w2 writes x2u
  u16* hb   = vb;          // reuse: vb+xcb+dtb = exactly 48 MB contiguous, all dead
                           // after scan_fix; ff1 output (8192x3072 bf16 = 48 MB)

  const dim3 tb32(32, 8);
  // weight prep
  wtrans4<<<dim3(32, 32, 4), tb32, 0, stream>>>(w1_w, v1_w, w2_w, dt_w,
                                                wv1T, wv1T + (size_t)1024 * 1024,
                                                w2T, wcatT);
  small_trans<<<64, 256, 0, stream>>>(Bp_w, Cp_w, wcatT);
  wtrans<<<dim3(96, 32), tb32, 0, stream>>>(ff1_w, ff1T, 1024, 3072, 0, 1024);
  wtrans<<<dim3(32, 96), tb32, 0, stream>>>(ff2_w, ff2T, 3072, 1024, 0, 3072);

  // LN1 -> LN2 -> xm (bf16)
  ln_ln_kernel<<<NTOK, 256, 0, stream>>>(x, ln1_g, ln1_b, ln_g, ln_b, xm);

  // fused: x1 = xm @ w1 + b ; v = silu(xm @ v1 + b)   (N=2048; 256-row tile, 8 waves)
  gemm_bt<5, 128, 1, 4><<<512, 512, 0, stream>>>(xm, wv1T, w1_b, v1_b, nullptr, nullptr,
                                                 x1b, vb, 1024, 1024, 16);

  // xc = silu(depthwise_conv(x1))
  conv_silu_kernel<<<(NTOK * DM) / (256 * 8), 256, 0, stream>>>(x1b, conv_w, xcb);

  // dt (bf16, softplus) + BC (compact f32): N=1088 grid (cols>=1088 all-pad skipped)
  gemm_bt<4, 64, 1, 2><<<1088, 256, 0, stream>>>(xcb, wcatT, dt_b, Bp_b, Cp_b, nullptr,
                                                 dtb, bcb, 1024, 1024, 17);

  // chunked selective scan: local scan (+ y_local, cumdt) -> combine -> parallel fix
  scan_pass1<<<2048, 256, 0, stream>>>(xcb, dtb, bcb, A_log, D_p, hloc, sdtb, ylb, cdb);
  scan_pass2<<<256, 256, 0, stream>>>(A_log, sdtb, hloc, hin);
  scan_fix<<<2048, 256, 0, stream>>>(bcb, ylb, cdb, vb, A_log, hin, yvb);

  // x2 = yv @ w2 + b + x  (bf16 out, f32 resid)
  gemm_bt<6, 64, 1, 2><<<1024, 256, 0, stream>>>(yvb, w2T, w2_b, nullptr, nullptr, x,
                                                 x2u, nullptr, 1024, 1024, 16);

  // xn2 = LN(x2) (bf16 in/out)
  ln_bf_kernel<<<NTOK, 256, 0, stream>>>(x2u, ln2_g, ln2_b, xn2);

  // h = gelu(xn2 @ ff1 + b) (bf16, ld 3072; 256-row tile, 8 waves)
  gemm_bt<2, 128, 1, 4><<<768, 512, 0, stream>>>(xn2, ff1T, ff1_b, nullptr, nullptr, nullptr,
                                                 hb, nullptr, 1024, 3072, 24);

  // out = h @ ff2 + b + x2  (f32 out, bf16 resid; BK=64 pipeline)
  gemm_bt<7, 128, 2, 2><<<512, 256, 0, stream>>>(hb, ff2T, ff2_b, nullptr, nullptr,
                                                 (const float*)x2u, d_out, nullptr,
                                                 3072, 1024, 8);
}

// Round 13
// 390.959 us; speedup vs baseline: 1.0958x; 1.0320x over previous
//
#include <hip/hip_runtime.h>

typedef unsigned short u16;
typedef __attribute__((ext_vector_type(8))) short short8;
typedef __attribute__((ext_vector_type(4))) float f32x4;
typedef __attribute__((ext_vector_type(4))) unsigned short u16x4;

#define SEQ 2048
#define DM 1024
#define NTOK 8192  // B*L
#define CH 64      // scan chunk length
#define NCH 32     // SEQ / CH

__device__ __forceinline__ float b2f(u16 u) {
  union { float f; unsigned int i; } x; x.i = ((unsigned int)u) << 16; return x.f;
}
__device__ __forceinline__ u16 f2b(float f) {
  union { float f; unsigned int i; } x; x.f = f;
  unsigned int i = x.i;
  unsigned int r = (i + 0x7FFFu + ((i >> 16) & 1u)) >> 16;
  return (u16)r;
}

__device__ __forceinline__ void gload16(const u16* g, u16* l) {
  __builtin_amdgcn_global_load_lds(
      (const __attribute__((address_space(1))) void*)g,
      (__attribute__((address_space(3))) void*)l, 16, 0, 0);
}

// fast gelu (exact erf via Abramowitz-Stegun 7.1.26, |err| < 1.5e-7)
__device__ __forceinline__ float gelu_f(float v) {
  const float z = fabsf(v) * 0.70710678118f;
  const float t = __builtin_amdgcn_rcpf(1.f + 0.3275911f * z);
  float poly = ((((1.061405429f * t - 1.453152027f) * t + 1.421413741f) * t
                 - 0.284496736f) * t + 0.254829592f) * t;
  float e = 1.f - poly * __expf(-z * z);
  float erfv = (v < 0.f) ? -e : e;
  return 0.5f * v * (1.f + erfv);
}
__device__ __forceinline__ float silu_f(float v) {
  return v * __builtin_amdgcn_rcpf(1.f + __expf(-v));
}
__device__ __forceinline__ float softplus_f(float v) {
  return fmaxf(v, 0.f) + __logf(1.f + __expf(-fabsf(v)));
}

// ---------------- weight transpose f32 (K x N) -> bf16 (N x K) ----------------
__global__ __launch_bounds__(256)
void wtrans(const float* __restrict__ in, u16* __restrict__ out,
            int K, int N, int rowOff, int ldOut)
{
  __shared__ float tile[32][33];
  const int n0 = blockIdx.x * 32;
  const int k0 = blockIdx.y * 32;
  const int tx = threadIdx.x, ty = threadIdx.y;
#pragma unroll
  for (int i = 0; i < 32; i += 8) {
    int k = k0 + ty + i, n = n0 + tx;
    tile[ty + i][tx] = (k < K && n < N) ? in[(long)k * N + n] : 0.f;
  }
  __syncthreads();
#pragma unroll
  for (int i = 0; i < 32; i += 8) {
    int n = n0 + ty + i, k = k0 + tx;
    if (n < N && k < K) out[(long)(rowOff + n) * ldOut + k] = f2b(tile[tx][ty + i]);
  }
}

// four 1024x1024 transposes in one launch (z-indexed)
__global__ __launch_bounds__(256)
void wtrans4(const float* __restrict__ s0, const float* __restrict__ s1,
             const float* __restrict__ s2, const float* __restrict__ s3,
             u16* __restrict__ d0, u16* __restrict__ d1,
             u16* __restrict__ d2, u16* __restrict__ d3)
{
  __shared__ float tile[32][33];
  const float* in; u16* out;
  switch (blockIdx.z) {
    case 0: in = s0; out = d0; break;
    case 1: in = s1; out = d1; break;
    case 2: in = s2; out = d2; break;
    default: in = s3; out = d3; break;
  }
  const int n0 = blockIdx.x * 32;
  const int k0 = blockIdx.y * 32;
  const int tx = threadIdx.x, ty = threadIdx.y;
#pragma unroll
  for (int i = 0; i < 32; i += 8)
    tile[ty + i][tx] = in[(long)(k0 + ty + i) * 1024 + n0 + tx];
  __syncthreads();
#pragma unroll
  for (int i = 0; i < 32; i += 8)
    out[(long)(n0 + ty + i) * 1024 + k0 + tx] = f2b(tile[tx][ty + i]);
}

// Bp_w/Cp_w (1024x16) -> rows [1024..1055] of WcatT (ld 1024); zero rows 1056..1151
__global__ __launch_bounds__(256)
void small_trans(const float* __restrict__ Bp, const float* __restrict__ Cp,
                 u16* __restrict__ wcatT)
{
  int t = blockIdx.x * 256 + threadIdx.x;  // 16384 threads
  int n = t >> 10, k = t & 1023;
  wcatT[(long)(1024 + n) * 1024 + k] = f2b(Bp[(long)k * 16 + n]);
  wcatT[(long)(1040 + n) * 1024 + k] = f2b(Cp[(long)k * 16 + n]);
#pragma unroll
  for (int i = 0; i < 6; ++i)
    wcatT[(long)1056 * 1024 + i * 16384 + t] = 0;
}

// ---------------- LayerNorm helpers ----------------
__device__ __forceinline__ void blockReduce2(float& a, float& b, float* s)
{
#pragma unroll
  for (int off = 32; off > 0; off >>= 1) {
    a += __shfl_xor(a, off);
    b += __shfl_xor(b, off);
  }
  const int lane = threadIdx.x & 63, wid = threadIdx.x >> 6;
  __syncthreads();
  if (lane == 0) { s[wid] = a; s[4 + wid] = b; }
  __syncthreads();
  a = s[0] + s[1] + s[2] + s[3];
  b = s[4] + s[5] + s[6] + s[7];
}

// fused LN1 -> LN2, f32 in, bf16 out (row length 1024, 256 thr x 4 elems)
__global__ __launch_bounds__(256)
void ln_ln_kernel(const float* __restrict__ x, const float* __restrict__ g1,
                  const float* __restrict__ b1, const float* __restrict__ g2,
                  const float* __restrict__ b2, u16* __restrict__ out)
{
  __shared__ float sred[8];
  const long row = blockIdx.x;
  const int t = threadIdx.x;
  const float4 xv = ((const float4*)(x + row * DM))[t];
  float s = xv.x + xv.y + xv.z + xv.w;
  float sq = xv.x * xv.x + xv.y * xv.y + xv.z * xv.z + xv.w * xv.w;
  blockReduce2(s, sq, sred);
  const float mu = s * (1.f / DM);
  const float rs = rsqrtf(sq * (1.f / DM) - mu * mu + 1e-5f);
  const float4 g1v = ((const float4*)g1)[t];
  const float4 b1v = ((const float4*)b1)[t];
  float xn[4];
  xn[0] = (xv.x - mu) * rs * g1v.x + b1v.x;
  xn[1] = (xv.y - mu) * rs * g1v.y + b1v.y;
  xn[2] = (xv.z - mu) * rs * g1v.z + b1v.z;
  xn[3] = (xv.w - mu) * rs * g1v.w + b1v.w;
  float s2 = xn[0] + xn[1] + xn[2] + xn[3];
  float sq2 = xn[0] * xn[0] + xn[1] * xn[1] + xn[2] * xn[2] + xn[3] * xn[3];
  blockReduce2(s2, sq2, sred);
  const float mu2 = s2 * (1.f / DM);
  const float rs2 = rsqrtf(sq2 * (1.f / DM) - mu2 * mu2 + 1e-5f);
  const float4 g2v = ((const float4*)g2)[t];
  const float4 b2v = ((const float4*)b2)[t];
  u16x4 o;
  o[0] = f2b((xn[0] - mu2) * rs2 * g2v.x + b2v.x);
  o[1] = f2b((xn[1] - mu2) * rs2 * g2v.y + b2v.y);
  o[2] = f2b((xn[2] - mu2) * rs2 * g2v.z + b2v.z);
  o[3] = f2b((xn[3] - mu2) * rs2 * g2v.w + b2v.w);
  *(u16x4*)(out + row * DM + t * 4) = o;
}

// single LN, bf16 in, bf16 out
__global__ __launch_bounds__(256)
void ln_bf_kernel(const u16* __restrict__ x, const float* __restrict__ g,
                  const float* __restrict__ b, u16* __restrict__ out)
{
  __shared__ float sred[8];
  const long row = blockIdx.x;
  const int t = threadIdx.x;
  const u16x4 xv4 = ((const u16x4*)(x + row * DM))[t];
  float xv[4];
#pragma unroll
  for (int j = 0; j < 4; ++j) xv[j] = b2f(xv4[j]);
  float s = xv[0] + xv[1] + xv[2] + xv[3];
  float sq = xv[0] * xv[0] + xv[1] * xv[1] + xv[2] * xv[2] + xv[3] * xv[3];
  blockReduce2(s, sq, sred);
  const float mu = s * (1.f / DM);
  const float rs = rsqrtf(sq * (1.f / DM) - mu * mu + 1e-5f);
  const float4 gv = ((const float4*)g)[t];
  const float4 bv = ((const float4*)b)[t];
  u16x4 o;
  o[0] = f2b((xv[0] - mu) * rs * gv.x + bv.x);
  o[1] = f2b((xv[1] - mu) * rs * gv.y + bv.y);
  o[2] = f2b((xv[2] - mu) * rs * gv.z + bv.z);
  o[3] = f2b((xv[3] - mu) * rs * gv.w + bv.w);
  *(u16x4*)(out + row * DM + t * 4) = o;
}

// ---------------- depthwise conv (k=3, pad 1 along L) + silu, vectorized ----------------
__global__ __launch_bounds__(256)
void conv_silu_kernel(const u16* __restrict__ x1, const float* __restrict__ w,
                      u16* __restrict__ xc)
{
  const long i8 = (long)blockIdx.x * 256 + threadIdx.x;  // NTOK*DM/8
  const long base = i8 * 8;
  const int d0 = (int)(base & (DM - 1));
  const long m = base >> 10;
  const int l = (int)(m & (SEQ - 1));
  const short8 cv = *(const short8*)(x1 + base);
  short8 lv = {}, rv = {};
  if (l > 0) lv = *(const short8*)(x1 + base - DM);
  if (l < SEQ - 1) rv = *(const short8*)(x1 + base + DM);
  short8 o;
#pragma unroll
  for (int j = 0; j < 8; ++j) {
    const int d = d0 + j;
    const float a = b2f((u16)lv[j]) * w[d * 3 + 0] + b2f((u16)cv[j]) * w[d * 3 + 1]
                  + b2f((u16)rv[j]) * w[d * 3 + 2];
    o[j] = (short)f2b(silu_f(a));
  }
  *(short8*)(xc + base) = o;
}

// ---------------- GEMM: (WM*64)xBN tile, NU K-subtiles per barrier, WM*128 thr ----
// WM = waves along M (2 -> 128-row tile / 256 thr; 4 -> 256-row tile / 512 thr).
// MODE 2: bf16 out = gelu(acc + bias)
// MODE 4: dtBC: col<1024 -> bf16 softplus to outp (ld 1024); cols 1024..1055 -> f32
//         to outp2 (ld 32, +bias2/+bias3); col>=1056 skipped
// MODE 5: fused w1|v1 (N=2048): col<1024 -> outp (bf16, +bias); else silu -> outp2
// MODE 6: bf16 out = acc + bias + resid(f32)
// MODE 7: f32  out = acc + bias + resid(bf16)
template <int MODE, int BN, int NU, int WM>
__global__ __launch_bounds__(WM * 128)
void gemm_bt(const u16* __restrict__ A, const u16* __restrict__ BT,
             const float* __restrict__ bias, const float* __restrict__ bias2,
             const float* __restrict__ bias3, const float* __restrict__ resid,
             void* __restrict__ outp, void* __restrict__ outp2,
             int K, int ldOut, int nbx)
{
  constexpr int T = WM * 128;            // threads
  constexpr int NF = BN / 32;            // B col fragments per wave: 4 or 2
  constexpr int ASUB = WM * 2048;        // u16 per A subtile (WM*64 rows x 32)
  constexpr int ASZ = ASUB * NU;
  constexpr int BSUB = BN * 32;          // u16 per B subtile
  constexpr int BSZ = BSUB * NU;
  constexpr int BLOADS = (BN * 4) / T;   // B gloads per thread per subtile (1 or 2)
  static_assert(BLOADS >= 1, "bad BN/WM combo");
  __shared__ u16 lds_a[2][ASZ];
  __shared__ u16 lds_b[2][BSZ];
  const int t = threadIdx.x;
  const int lane = t & 63;
  const int wid = t >> 6;
  const int wr = wid >> 1, wc = wid & 1;  // wr in 0..WM-1

  int bid = blockIdx.x;
  const int qch = gridDim.x >> 3;
  bid = (bid & 7) * qch + (bid >> 3);
  const long brow = (long)(bid / nbx) * (WM * 64);
  const long bcol = (long)(bid % nbx) * BN;

  f32x4 acc[4][NF] = {};

  const int srow = t >> 2;               // 0..T/4-1
  const int sslot = (t & 3) ^ ((t >> 3) & 3);
  const u16* aPtr = A + (brow + srow) * (long)K + sslot * 8;
  const u16* bPtr = BT + (bcol + srow) * (long)K + sslot * 8;
  u16* la = &lds_a[0][t * 8];
  u16* lb = &lds_b[0][t * 8];
  const long rowStep = (long)(T >> 2) * K;   // T/4 rows per gload pass
  const int nk = K / (32 * NU);

  const int rslot = (lane >> 4) ^ ((lane >> 1) & 3);
  const int koff = rslot * 8;
  const int arow = wr * 64 + (lane & 15);
  const int brw = (BN == 128 ? wc * 64 : wc * 32) + (lane & 15);

#define STAGE(kt, buf)                                                        \
  {                                                                           \
    _Pragma("unroll")                                                         \
    for (int su_ = 0; su_ < NU; ++su_) {                                      \
      const int k0_ = (((kt) * NU + su_) << 5);                               \
      gload16(aPtr + k0_, la + (buf) * ASZ + su_ * ASUB);                     \
      gload16(aPtr + rowStep + k0_, la + (buf) * ASZ + su_ * ASUB + T * 8);   \
      gload16(bPtr + k0_, lb + (buf) * BSZ + su_ * BSUB);                     \
      if constexpr (BLOADS == 2)                                              \
        gload16(bPtr + rowStep + k0_, lb + (buf) * BSZ + su_ * BSUB + T * 8); \
    }                                                                         \
  }

  STAGE(0, 0);
  __syncthreads();
  int cur = 0;
  for (int kt = 0; kt < nk; ++kt) {
    if (kt + 1 < nk) STAGE(kt + 1, cur ^ 1);
#pragma unroll
    for (int su = 0; su < NU; ++su) {
      const u16* pa = &lds_a[cur][su * ASUB];
      const u16* pb = &lds_b[cur][su * BSUB];
      short8 af[4], bfr[NF];
#pragma unroll
      for (int m = 0; m < 4; ++m)
        af[m] = *(const short8*)&pa[(arow + m * 16) * 32 + koff];
#pragma unroll
      for (int n = 0; n < NF; ++n)
        bfr[n] = *(const short8*)&pb[(brw + n * 16) * 32 + koff];
#pragma unroll
      for (int m = 0; m < 4; ++m)
#pragma unroll
        for (int n = 0; n < NF; ++n)
          acc[m][n] = __builtin_amdgcn_mfma_f32_16x16x32_bf16(af[m], bfr[n], acc[m][n], 0, 0, 0);
    }
    __syncthreads();
    cur ^= 1;
  }
#undef STAGE

  const int cc = lane & 15;
  const int r0 = (lane >> 4) * 4;
#pragma unroll
  for (int m = 0; m < 4; ++m) {
#pragma unroll
    for (int n = 0; n < NF; ++n) {
      const long col = bcol + (BN == 128 ? wc * 64 : wc * 32) + n * 16 + cc;
#pragma unroll
      for (int r = 0; r < 4; ++r) {
        const long row = brow + wr * 64 + m * 16 + r0 + r;
        float val = acc[m][n][r];
        if constexpr (MODE == 4) {
          if (col < 1024) {
            ((u16*)outp)[row * 1024 + col] = f2b(softplus_f(val + bias[col]));
          } else if (col < 1040) {
            ((float*)outp2)[row * 32 + col - 1024] = val + bias2[col - 1024];
          } else if (col < 1056) {
            ((float*)outp2)[row * 32 + col - 1024] = val + bias3[col - 1040];
          }
        } else if constexpr (MODE == 5) {
          if (col < 1024) {
            val += bias[col];
            ((u16*)outp)[row * 1024 + col] = f2b(val);
          } else {
            ((u16*)outp2)[row * 1024 + col - 1024] = f2b(silu_f(val + bias2[col - 1024]));
          }
        } else if constexpr (MODE == 6) {
          val += bias[col];
          ((u16*)outp)[row * ldOut + col] = f2b(val + resid[row * ldOut + col]);
        } else if constexpr (MODE == 7) {
          val += bias[col];
          ((float*)outp)[row * ldOut + col] = val + b2f(((const u16*)resid)[row * ldOut + col]);
        } else {  // MODE 2
          ((u16*)outp)[row * ldOut + col] = f2b(gelu_f(val + bias[col]));
        }
      }
    }
  }
}

// ---------------- chunked selective scan ----------------
// pass 1: local scan (h0=0): h_out/chunk + sum(dt) + y_local + inclusive cumdt (bf16)
__global__ __launch_bounds__(256)
void scan_pass1(const u16* __restrict__ xc, const u16* __restrict__ dtb,
                const float* __restrict__ bcb, const float* __restrict__ A_log,
                const float* __restrict__ D_p, float* __restrict__ hloc,
                float* __restrict__ sdt, u16* __restrict__ ylb, u16* __restrict__ cdb)
{
  const int bx = blockIdx.x;
  const int b = bx >> 9;
  const int ch = (bx >> 4) & 31;
  const int dBase = (bx & 15) * 64;
  const int t = threadIdx.x;
  const int dl = t >> 2;
  const int q = t & 3;
  const int d = dBase + dl;

  __shared__ float s_bc[32][32];
  __shared__ u16 s_dt[32][64];
  __shared__ u16 s_x[32][64];
  __shared__ u16 s_yl[32][64];
  __shared__ u16 s_cd[32][64];

  float Areg[4];
#pragma unroll
  for (int j = 0; j < 4; ++j) Areg[j] = -__expf(A_log[d * 16 + q * 4 + j]);
  const float Dp = D_p[d];
  float h[4] = {0.f, 0.f, 0.f, 0.f};
  float sAcc = 0.f;
  const long mBase = (long)b * SEQ + ch * CH;

  for (int c0 = 0; c0 < CH; c0 += 32) {
#pragma unroll
    for (int i = 0; i < 4; ++i) {
      int idx = i * 256 + t;
      int s = idx >> 5, j = idx & 31;
      s_bc[s][j] = bcb[(mBase + c0 + s) * 32 + j];
    }
#pragma unroll
    for (int i = 0; i < 8; ++i) {
      int idx = i * 256 + t;
      int s = idx >> 6, j = idx & 63;
      long m = mBase + c0 + s;
      s_dt[s][j] = dtb[m * DM + dBase + j];
      s_x[s][j] = xc[m * DM + dBase + j];
    }
    __syncthreads();
#pragma unroll 4
    for (int s = 0; s < 32; ++s) {
      const float dt = b2f(s_dt[s][dl]);
      const float xt = b2f(s_x[s][dl]);
      const float p = dt * xt;
      sAcc += dt;
      float y = 0.f;
#pragma unroll
      for (int j = 0; j < 4; ++j) {
        h[j] = __expf(dt * Areg[j]) * h[j] + p * s_bc[s][q * 4 + j];
        y = fmaf(h[j], s_bc[s][16 + q * 4 + j], y);
      }
      y += __shfl_xor(y, 1);
      y += __shfl_xor(y, 2);
      if (q == 0) s_yl[s][dl] = f2b(y + Dp * xt);
      if (q == 1) s_cd[s][dl] = f2b(sAcc);
    }
    __syncthreads();
#pragma unroll
    for (int i = 0; i < 8; ++i) {
      int idx = i * 256 + t;
      int s = idx >> 6, j = idx & 63;
      long m = mBase + c0 + s;
      ylb[m * DM + dBase + j] = s_yl[s][j];
      cdb[m * DM + dBase + j] = s_cd[s][j];
    }
    __syncthreads();
  }
  const long base = (((long)b * NCH + ch) * 1024 + d) * 16 + q * 4;
  float4 hv; hv.x = h[0]; hv.y = h[1]; hv.z = h[2]; hv.w = h[3];
  *(float4*)&hloc[base] = hv;
  if (q == 0) sdt[((long)b * NCH + ch) * 1024 + d] = sAcc;
}

// pass 2: sequential combine over chunks
__global__ __launch_bounds__(256)
void scan_pass2(const float* __restrict__ A_log, const float* __restrict__ sdt,
                const float* __restrict__ hloc, float* __restrict__ hin)
{
  const int tid = blockIdx.x * 256 + threadIdx.x;
  const int b = tid >> 14;
  const int dn = tid & 16383;
  const int d = dn >> 4;
  const float A = -__expf(A_log[dn]);
  float h = 0.f;
  for (int c = 0; c < NCH; ++c) {
    const long idx = (((long)b * NCH + c) << 14) + dn;
    hin[idx] = h;
    h = __expf(A * sdt[((long)b * NCH + c) * 1024 + d]) * h + hloc[idx];
  }
}

// pass 3 (parallel): yv = (y_local + sum_n C[t,n]*hin[n]*exp(A_n*cumdt)) * v
__global__ __launch_bounds__(256)
void scan_fix(const float* __restrict__ bcb, const u16* __restrict__ ylb,
              const u16* __restrict__ cdb, const u16* __restrict__ vg,
              const float* __restrict__ A_log, const float* __restrict__ hin,
              u16* __restrict__ yv)
{
  const int bx = blockIdx.x;
  const int b = bx >> 9;
  const int ch = (bx >> 4) & 31;
  const int dBase = (bx & 15) * 64;
  const int t = threadIdx.x;
  const int dl = t >> 2;
  const int q = t & 3;
  const int d = dBase + dl;

  __shared__ float s_c[32][16];
  __shared__ u16 s_cd[32][64];
  __shared__ u16 s_yl[32][64];
  __shared__ u16 s_v[32][64];
  __shared__ u16 s_o[32][64];

  float Areg[4];
#pragma unroll
  for (int j = 0; j < 4; ++j) Areg[j] = -__expf(A_log[d * 16 + q * 4 + j]);
  const float4 hv4 = *(const float4*)&hin[(((long)b * NCH + ch) * 1024 + d) * 16 + q * 4];
  const float hv[4] = {hv4.x, hv4.y, hv4.z, hv4.w};

  const long mBase = (long)b * SEQ + ch * CH;

  for (int c0 = 0; c0 < CH; c0 += 32) {
#pragma unroll
    for (int i = 0; i < 2; ++i) {
      int idx = i * 256 + t;
      int s = idx >> 4, j = idx & 15;
      s_c[s][j] = bcb[(mBase + c0 + s) * 32 + 16 + j];
    }
#pragma unroll
    for (int i = 0; i < 8; ++i) {
      int idx = i * 256 + t;
      int s = idx >> 6, j = idx & 63;
      long m = mBase + c0 + s;
      s_cd[s][j] = cdb[m * DM + dBase + j];
      s_yl[s][j] = ylb[m * DM + dBase + j];
      s_v[s][j] = vg[m * DM + dBase + j];
    }
    __syncthreads();
#pragma unroll 4
    for (int s = 0; s < 32; ++s) {
      const float cd = b2f(s_cd[s][dl]);
      float corr = 0.f;
#pragma unroll
      for (int j = 0; j < 4; ++j)
        corr = fmaf(s_c[s][q * 4 + j] * hv[j], __expf(Areg[j] * cd), corr);
      corr += __shfl_xor(corr, 1);
      corr += __shfl_xor(corr, 2);
      if (q == 0)
        s_o[s][dl] = f2b((b2f(s_yl[s][dl]) + corr) * b2f(s_v[s][dl]));
    }
    __syncthreads();
#pragma unroll
    for (int i = 0; i < 8; ++i) {
      int idx = i * 256 + t;
      int s = idx >> 6, j = idx & 63;
      yv[(mBase + c0 + s) * DM + dBase + j] = s_o[s][j];
    }
    __syncthreads();
  }
}

extern "C" void kernel_launch(void* const* d_in, const int* in_sizes, int n_in,
                              void* d_out, int out_size, void* d_ws, size_t ws_size,
                              hipStream_t stream)
{
  (void)in_sizes; (void)n_in; (void)out_size; (void)ws_size;
  const float* x      = (const float*)d_in[0];
  const float* ln1_g  = (const float*)d_in[1];
  const float* ln1_b  = (const float*)d_in[2];
  const float* ln_g   = (const float*)d_in[3];
  const float* ln_b   = (const float*)d_in[4];
  const float* w1_w   = (const float*)d_in[5];
  const float* w1_b   = (const float*)d_in[6];
  const float* v1_w   = (const float*)d_in[7];
  const float* v1_b   = (const float*)d_in[8];
  const float* w2_w   = (const float*)d_in[9];
  const float* w2_b   = (const float*)d_in[10];
  const float* conv_w = (const float*)d_in[11];
  const float* dt_w   = (const float*)d_in[12];
  const float* dt_b   = (const float*)d_in[13];
  const float* Bp_w   = (const float*)d_in[14];
  const float* Bp_b   = (const float*)d_in[15];
  const float* Cp_w   = (const float*)d_in[16];
  const float* Cp_b   = (const float*)d_in[17];
  const float* A_log  = (const float*)d_in[18];
  const float* D_p    = (const float*)d_in[19];
  const float* ln2_g  = (const float*)d_in[20];
  const float* ln2_b  = (const float*)d_in[21];
  const float* ff1_w  = (const float*)d_in[22];
  const float* ff1_b  = (const float*)d_in[23];
  const float* ff2_w  = (const float*)d_in[24];
  const float* ff2_b  = (const float*)d_in[25];

  char* ws = (char*)d_ws;
  size_t cur = 0;
  auto alloc = [&](size_t bytes) -> void* {
    void* p = ws + cur;
    cur = (cur + bytes + 255) & ~(size_t)255;
    return p;
  };

  u16* wv1T  = (u16*)alloc((size_t)2048 * 1024 * 2);   // [w1T ; v1T]
  u16* w2T   = (u16*)alloc((size_t)1024 * 1024 * 2);
  u16* wcatT = (u16*)alloc((size_t)1152 * 1024 * 2);
  u16* ff1T  = (u16*)alloc((size_t)3072 * 1024 * 2);
  u16* ff2T  = (u16*)alloc((size_t)1024 * 3072 * 2);
  u16* xm    = (u16*)alloc((size_t)NTOK * DM * 2);
  u16* x1b   = (u16*)alloc((size_t)NTOK * DM * 2);
  u16* vb    = (u16*)alloc((size_t)NTOK * DM * 2);     // 16 MB
  u16* xcb   = (u16*)alloc((size_t)NTOK * DM * 2);     // 16 MB (contiguous after vb)
  u16* dtb   = (u16*)alloc((size_t)NTOK * DM * 2);     // 16 MB (contiguous after xcb)
  float* bcb = (float*)alloc((size_t)NTOK * 32 * 4);   // [B|C] compact f32
  u16* x2u   = (u16*)alloc((size_t)NTOK * DM * 2);     // x2 bf16
  float* hloc = (float*)alloc((size_t)4 * NCH * 1024 * 16 * 4);  // 8 MB
  float* hin  = (float*)alloc((size_t)4 * NCH * 1024 * 16 * 4);  // 8 MB
  float* sdtb = (float*)alloc((size_t)4 * NCH * 1024 * 4);       // 512 KB
  u16* yvb  = xm;          // reuse: xm dead after fused GEMM; consumed by w2
  u16* ylb  = x1b;         // reuse: x1 dead after conv; consumed by scan_fix
  u16* xn2  = x1b;         // reuse: ylb dead before LN writes xn2
  u16* cdb  = x2u;         // reuse: consumed by scan_fix before w2 writes x2u
  u16* hb   = vb;          // reuse: vb+xcb+dtb = exactly 48 MB contiguous, all dead
                           // after scan_fix; ff1 output (8192x3072 bf16 = 48 MB)

  const dim3 tb32(32, 8);
  // weight prep
  wtrans4<<<dim3(32, 32, 4), tb32, 0, stream>>>(w1_w, v1_w, w2_w, dt_w,
                                                wv1T, wv1T + (size_t)1024 * 1024,
                                                w2T, wcatT);
  small_trans<<<64, 256, 0, stream>>>(Bp_w, Cp_w, wcatT);
  wtrans<<<dim3(96, 32), tb32, 0, stream>>>(ff1_w, ff1T, 1024, 3072, 0, 1024);
  wtrans<<<dim3(32, 96), tb32, 0, stream>>>(ff2_w, ff2T, 3072, 1024, 0, 3072);

  // LN1 -> LN2 -> xm (bf16)
  ln_ln_kernel<<<NTOK, 256, 0, stream>>>(x, ln1_g, ln1_b, ln_g, ln_b, xm);

  // fused: x1 = xm @ w1 + b ; v = silu(xm @ v1 + b)   (N=2048; 256-row tile, 8 waves)
  gemm_bt<5, 128, 1, 4><<<512, 512, 0, stream>>>(xm, wv1T, w1_b, v1_b, nullptr, nullptr,
                                                 x1b, vb, 1024, 1024, 16);

  // xc = silu(depthwise_conv(x1))
  conv_silu_kernel<<<(NTOK * DM) / (256 * 8), 256, 0, stream>>>(x1b, conv_w, xcb);

  // dt (bf16, softplus) + BC (compact f32): N=1088 grid; NU=2 (barriers halved,
  // LDS 48 KB -> residency unchanged at ~2 blocks/CU)
  gemm_bt<4, 64, 2, 2><<<1088, 256, 0, stream>>>(xcb, wcatT, dt_b, Bp_b, Cp_b, nullptr,
                                                 dtb, bcb, 1024, 1024, 17);

  // chunked selective scan: local scan (+ y_local, cumdt) -> combine -> parallel fix
  scan_pass1<<<2048, 256, 0, stream>>>(xcb, dtb, bcb, A_log, D_p, hloc, sdtb, ylb, cdb);
  scan_pass2<<<256, 256, 0, stream>>>(A_log, sdtb, hloc, hin);
  scan_fix<<<2048, 256, 0, stream>>>(bcb, ylb, cdb, vb, A_log, hin, yvb);

  // x2 = yv @ w2 + b + x  (bf16 out, f32 resid; NU=2)
  gemm_bt<6, 64, 2, 2><<<1024, 256, 0, stream>>>(yvb, w2T, w2_b, nullptr, nullptr, x,
                                                 x2u, nullptr, 1024, 1024, 16);

  // xn2 = LN(x2) (bf16 in/out)
  ln_bf_kernel<<<NTOK, 256, 0, stream>>>(x2u, ln2_g, ln2_b, xn2);

  // h = gelu(xn2 @ ff1 + b) (bf16, ld 3072; 256-row tile, 8 waves)
  gemm_bt<2, 128, 1, 4><<<768, 512, 0, stream>>>(xn2, ff1T, ff1_b, nullptr, nullptr, nullptr,
                                                 hb, nullptr, 1024, 3072, 24);

  // out = h @ ff2 + b + x2  (f32 out, bf16 resid; BK=64 pipeline)
  gemm_bt<7, 128, 2, 2><<<512, 256, 0, stream>>>(hb, ff2T, ff2_b, nullptr, nullptr,
                                                 (const float*)x2u, d_out, nullptr,
                                                 3072, 1024, 8);
}

// Round 14
// 384.241 us; speedup vs baseline: 1.1149x; 1.0175x over previous
//
#include <hip/hip_runtime.h>

typedef unsigned short u16;
typedef __attribute__((ext_vector_type(8))) short short8;
typedef __attribute__((ext_vector_type(4))) float f32x4;
typedef __attribute__((ext_vector_type(4))) unsigned short u16x4;

#define SEQ 2048
#define DM 1024
#define NTOK 8192  // B*L
#define CH 64      // scan chunk length
#define NCH 32     // SEQ / CH

__device__ __forceinline__ float b2f(u16 u) {
  union { float f; unsigned int i; } x; x.i = ((unsigned int)u) << 16; return x.f;
}
__device__ __forceinline__ u16 f2b(float f) {
  union { float f; unsigned int i; } x; x.f = f;
  unsigned int i = x.i;
  unsigned int r = (i + 0x7FFFu + ((i >> 16) & 1u)) >> 16;
  return (u16)r;
}

__device__ __forceinline__ void gload16(const u16* g, u16* l) {
  __builtin_amdgcn_global_load_lds(
      (const __attribute__((address_space(1))) void*)g,
      (__attribute__((address_space(3))) void*)l, 16, 0, 0);
}

// fast gelu (exact erf via Abramowitz-Stegun 7.1.26, |err| < 1.5e-7)
__device__ __forceinline__ float gelu_f(float v) {
  const float z = fabsf(v) * 0.70710678118f;
  const float t = __builtin_amdgcn_rcpf(1.f + 0.3275911f * z);
  float poly = ((((1.061405429f * t - 1.453152027f) * t + 1.421413741f) * t
                 - 0.284496736f) * t + 0.254829592f) * t;
  float e = 1.f - poly * __expf(-z * z);
  float erfv = (v < 0.f) ? -e : e;
  return 0.5f * v * (1.f + erfv);
}
__device__ __forceinline__ float silu_f(float v) {
  return v * __builtin_amdgcn_rcpf(1.f + __expf(-v));
}
__device__ __forceinline__ float softplus_f(float v) {
  return fmaxf(v, 0.f) + __logf(1.f + __expf(-fabsf(v)));
}

// four 1024x1024 transposes in one launch (z-indexed)
__global__ __launch_bounds__(256)
void wtrans4(const float* __restrict__ s0, const float* __restrict__ s1,
             const float* __restrict__ s2, const float* __restrict__ s3,
             u16* __restrict__ d0, u16* __restrict__ d1,
             u16* __restrict__ d2, u16* __restrict__ d3)
{
  __shared__ float tile[32][33];
  const float* in; u16* out;
  switch (blockIdx.z) {
    case 0: in = s0; out = d0; break;
    case 1: in = s1; out = d1; break;
    case 2: in = s2; out = d2; break;
    default: in = s3; out = d3; break;
  }
  const int n0 = blockIdx.x * 32;
  const int k0 = blockIdx.y * 32;
  const int tx = threadIdx.x, ty = threadIdx.y;
#pragma unroll
  for (int i = 0; i < 32; i += 8)
    tile[ty + i][tx] = in[(long)(k0 + ty + i) * 1024 + n0 + tx];
  __syncthreads();
#pragma unroll
  for (int i = 0; i < 32; i += 8)
    out[(long)(n0 + ty + i) * 1024 + k0 + tx] = f2b(tile[tx][ty + i]);
}

// ff1_w (1024x3072) -> ff1T (3072x1024) and ff2_w (3072x1024) -> ff2T (1024x3072)
// in one 1-D launch: blocks 0..3071 = ff1, 3072..6143 = ff2
__global__ __launch_bounds__(256)
void wtrans_ff(const float* __restrict__ ff1w, const float* __restrict__ ff2w,
               u16* __restrict__ ff1T, u16* __restrict__ ff2T)
{
  __shared__ float tile[32][33];
  int bid = blockIdx.x;
  const float* in; u16* out; int n0, k0, N, ldOut;
  if (bid < 3072) {
    in = ff1w; out = ff1T; n0 = (bid % 96) * 32; k0 = (bid / 96) * 32;
    N = 3072; ldOut = 1024;
  } else {
    bid -= 3072;
    in = ff2w; out = ff2T; n0 = (bid % 32) * 32; k0 = (bid / 32) * 32;
    N = 1024; ldOut = 3072;
  }
  const int tx = threadIdx.x, ty = threadIdx.y;
#pragma unroll
  for (int i = 0; i < 32; i += 8)
    tile[ty + i][tx] = in[(long)(k0 + ty + i) * N + n0 + tx];
  __syncthreads();
#pragma unroll
  for (int i = 0; i < 32; i += 8)
    out[(long)(n0 + ty + i) * ldOut + k0 + tx] = f2b(tile[tx][ty + i]);
}

// Bp_w/Cp_w (1024x16) -> rows [1024..1055] of WcatT (ld 1024); zero rows 1056..1151
__global__ __launch_bounds__(256)
void small_trans(const float* __restrict__ Bp, const float* __restrict__ Cp,
                 u16* __restrict__ wcatT)
{
  int t = blockIdx.x * 256 + threadIdx.x;  // 16384 threads
  int n = t >> 10, k = t & 1023;
  wcatT[(long)(1024 + n) * 1024 + k] = f2b(Bp[(long)k * 16 + n]);
  wcatT[(long)(1040 + n) * 1024 + k] = f2b(Cp[(long)k * 16 + n]);
#pragma unroll
  for (int i = 0; i < 6; ++i)
    wcatT[(long)1056 * 1024 + i * 16384 + t] = 0;
}

// ---------------- LayerNorm helpers ----------------
__device__ __forceinline__ void blockReduce2(float& a, float& b, float* s)
{
#pragma unroll
  for (int off = 32; off > 0; off >>= 1) {
    a += __shfl_xor(a, off);
    b += __shfl_xor(b, off);
  }
  const int lane = threadIdx.x & 63, wid = threadIdx.x >> 6;
  __syncthreads();
  if (lane == 0) { s[wid] = a; s[4 + wid] = b; }
  __syncthreads();
  a = s[0] + s[1] + s[2] + s[3];
  b = s[4] + s[5] + s[6] + s[7];
}

// fused LN1 -> LN2, f32 in, bf16 out (row length 1024, 256 thr x 4 elems)
__global__ __launch_bounds__(256)
void ln_ln_kernel(const float* __restrict__ x, const float* __restrict__ g1,
                  const float* __restrict__ b1, const float* __restrict__ g2,
                  const float* __restrict__ b2, u16* __restrict__ out)
{
  __shared__ float sred[8];
  const long row = blockIdx.x;
  const int t = threadIdx.x;
  const float4 xv = ((const float4*)(x + row * DM))[t];
  float s = xv.x + xv.y + xv.z + xv.w;
  float sq = xv.x * xv.x + xv.y * xv.y + xv.z * xv.z + xv.w * xv.w;
  blockReduce2(s, sq, sred);
  const float mu = s * (1.f / DM);
  const float rs = rsqrtf(sq * (1.f / DM) - mu * mu + 1e-5f);
  const float4 g1v = ((const float4*)g1)[t];
  const float4 b1v = ((const float4*)b1)[t];
  float xn[4];
  xn[0] = (xv.x - mu) * rs * g1v.x + b1v.x;
  xn[1] = (xv.y - mu) * rs * g1v.y + b1v.y;
  xn[2] = (xv.z - mu) * rs * g1v.z + b1v.z;
  xn[3] = (xv.w - mu) * rs * g1v.w + b1v.w;
  float s2 = xn[0] + xn[1] + xn[2] + xn[3];
  float sq2 = xn[0] * xn[0] + xn[1] * xn[1] + xn[2] * xn[2] + xn[3] * xn[3];
  blockReduce2(s2, sq2, sred);
  const float mu2 = s2 * (1.f / DM);
  const float rs2 = rsqrtf(sq2 * (1.f / DM) - mu2 * mu2 + 1e-5f);
  const float4 g2v = ((const float4*)g2)[t];
  const float4 b2v = ((const float4*)b2)[t];
  u16x4 o;
  o[0] = f2b((xn[0] - mu2) * rs2 * g2v.x + b2v.x);
  o[1] = f2b((xn[1] - mu2) * rs2 * g2v.y + b2v.y);
  o[2] = f2b((xn[2] - mu2) * rs2 * g2v.z + b2v.z);
  o[3] = f2b((xn[3] - mu2) * rs2 * g2v.w + b2v.w);
  *(u16x4*)(out + row * DM + t * 4) = o;
}

// single LN, bf16 in, bf16 out
__global__ __launch_bounds__(256)
void ln_bf_kernel(const u16* __restrict__ x, const float* __restrict__ g,
                  const float* __restrict__ b, u16* __restrict__ out)
{
  __shared__ float sred[8];
  const long row = blockIdx.x;
  const int t = threadIdx.x;
  const u16x4 xv4 = ((const u16x4*)(x + row * DM))[t];
  float xv[4];
#pragma unroll
  for (int j = 0; j < 4; ++j) xv[j] = b2f(xv4[j]);
  float s = xv[0] + xv[1] + xv[2] + xv[3];
  float sq = xv[0] * xv[0] + xv[1] * xv[1] + xv[2] * xv[2] + xv[3] * xv[3];
  blockReduce2(s, sq, sred);
  const float mu = s * (1.f / DM);
  const float rs = rsqrtf(sq * (1.f / DM) - mu * mu + 1e-5f);
  const float4 gv = ((const float4*)g)[t];
  const float4 bv = ((const float4*)b)[t];
  u16x4 o;
  o[0] = f2b((xv[0] - mu) * rs * gv.x + bv.x);
  o[1] = f2b((xv[1] - mu) * rs * gv.y + bv.y);
  o[2] = f2b((xv[2] - mu) * rs * gv.z + bv.z);
  o[3] = f2b((xv[3] - mu) * rs * gv.w + bv.w);
  *(u16x4*)(out + row * DM + t * 4) = o;
}

// ---------------- depthwise conv (k=3, pad 1 along L) + silu, vectorized ----------------
__global__ __launch_bounds__(256)
void conv_silu_kernel(const u16* __restrict__ x1, const float* __restrict__ w,
                      u16* __restrict__ xc)
{
  const long i8 = (long)blockIdx.x * 256 + threadIdx.x;  // NTOK*DM/8
  const long base = i8 * 8;
  const int d0 = (int)(base & (DM - 1));
  const long m = base >> 10;
  const int l = (int)(m & (SEQ - 1));
  const short8 cv = *(const short8*)(x1 + base);
  short8 lv = {}, rv = {};
  if (l > 0) lv = *(const short8*)(x1 + base - DM);
  if (l < SEQ - 1) rv = *(const short8*)(x1 + base + DM);
  short8 o;
#pragma unroll
  for (int j = 0; j < 8; ++j) {
    const int d = d0 + j;
    const float a = b2f((u16)lv[j]) * w[d * 3 + 0] + b2f((u16)cv[j]) * w[d * 3 + 1]
                  + b2f((u16)rv[j]) * w[d * 3 + 2];
    o[j] = (short)f2b(silu_f(a));
  }
  *(short8*)(xc + base) = o;
}

// ---------------- GEMM: (WM*64)xBN tile, NU K-subtiles per barrier, WM*128 thr ----
// WM = waves along M (2 -> 128-row tile / 256 thr; 4 -> 256-row tile / 512 thr).
// MODE 2: bf16 out = gelu(acc + bias)
// MODE 4: dtBC: col<1024 -> bf16 softplus to outp (ld 1024); cols 1024..1055 -> f32
//         to outp2 (ld 32, +bias2/+bias3); col>=1056 skipped
// MODE 5: fused w1|v1 (N=2048): col<1024 -> outp (bf16, +bias); else silu -> outp2
// MODE 6: bf16 out = acc + bias + resid(f32)
// MODE 7: f32  out = acc + bias + resid(bf16)
template <int MODE, int BN, int NU, int WM>
__global__ __launch_bounds__(WM * 128)
void gemm_bt(const u16* __restrict__ A, const u16* __restrict__ BT,
             const float* __restrict__ bias, const float* __restrict__ bias2,
             const float* __restrict__ bias3, const float* __restrict__ resid,
             void* __restrict__ outp, void* __restrict__ outp2,
             int K, int ldOut, int nbx)
{
  constexpr int T = WM * 128;            // threads
  constexpr int NF = BN / 32;            // B col fragments per wave: 4 or 2
  constexpr int ASUB = WM * 2048;        // u16 per A subtile (WM*64 rows x 32)
  constexpr int ASZ = ASUB * NU;
  constexpr int BSUB = BN * 32;          // u16 per B subtile
  constexpr int BSZ = BSUB * NU;
  __shared__ u16 lds_a[2][ASZ];
  __shared__ u16 lds_b[2][BSZ];
  const int t = threadIdx.x;
  const int lane = t & 63;
  const int wid = t >> 6;
  const int wr = wid >> 1, wc = wid & 1;  // wr in 0..WM-1

  int bid = blockIdx.x;
  const int qch = gridDim.x >> 3;
  bid = (bid & 7) * qch + (bid >> 3);
  const long brow = (long)(bid / nbx) * (WM * 64);
  const long bcol = (long)(bid % nbx) * BN;

  f32x4 acc[4][NF] = {};

  const int srow = t >> 2;               // 0..T/4-1
  const int sslot = (t & 3) ^ ((t >> 3) & 3);
  const u16* aPtr = A + (brow + srow) * (long)K + sslot * 8;
  const u16* bPtr = BT + (bcol + srow) * (long)K + sslot * 8;
  u16* la = &lds_a[0][t * 8];
  u16* lb = &lds_b[0][t * 8];
  const long rowStep = (long)(T >> 2) * K;   // T/4 rows per gload pass
  const int nk = K / (32 * NU);

  const int rslot = (lane >> 4) ^ ((lane >> 1) & 3);
  const int koff = rslot * 8;
  const int arow = wr * 64 + (lane & 15);
  const int brw = (BN == 128 ? wc * 64 : wc * 32) + (lane & 15);

#define STAGE(kt, buf)                                                        \
  {                                                                           \
    _Pragma("unroll")                                                         \
    for (int su_ = 0; su_ < NU; ++su_) {                                      \
      const int k0_ = (((kt) * NU + su_) << 5);                               \
      gload16(aPtr + k0_, la + (buf) * ASZ + su_ * ASUB);                     \
      gload16(aPtr + rowStep + k0_, la + (buf) * ASZ + su_ * ASUB + T * 8);   \
      if constexpr (BN * 4 >= T) {                                            \
        gload16(bPtr + k0_, lb + (buf) * BSZ + su_ * BSUB);                   \
        if constexpr (BN * 4 == 2 * T)                                        \
          gload16(bPtr + rowStep + k0_, lb + (buf) * BSZ + su_ * BSUB + T * 8); \
      } else {                                                                \
        if (t < BN * 4)                                                       \
          gload16(bPtr + k0_, lb + (buf) * BSZ + su_ * BSUB);                 \
      }                                                                       \
    }                                                                         \
  }

  STAGE(0, 0);
  __syncthreads();
  int cur = 0;
  for (int kt = 0; kt < nk; ++kt) {
    if (kt + 1 < nk) STAGE(kt + 1, cur ^ 1);
#pragma unroll
    for (int su = 0; su < NU; ++su) {
      const u16* pa = &lds_a[cur][su * ASUB];
      const u16* pb = &lds_b[cur][su * BSUB];
      short8 af[4], bfr[NF];
#pragma unroll
      for (int m = 0; m < 4; ++m)
        af[m] = *(const short8*)&pa[(arow + m * 16) * 32 + koff];
#pragma unroll
      for (int n = 0; n < NF; ++n)
        bfr[n] = *(const short8*)&pb[(brw + n * 16) * 32 + koff];
#pragma unroll
      for (int m = 0; m < 4; ++m)
#pragma unroll
        for (int n = 0; n < NF; ++n)
          acc[m][n] = __builtin_amdgcn_mfma_f32_16x16x32_bf16(af[m], bfr[n], acc[m][n], 0, 0, 0);
    }
    __syncthreads();
    cur ^= 1;
  }
#undef STAGE

  const int cc = lane & 15;
  const int r0 = (lane >> 4) * 4;
#pragma unroll
  for (int m = 0; m < 4; ++m) {
#pragma unroll
    for (int n = 0; n < NF; ++n) {
      const long col = bcol + (BN == 128 ? wc * 64 : wc * 32) + n * 16 + cc;
#pragma unroll
      for (int r = 0; r < 4; ++r) {
        const long row = brow + wr * 64 + m * 16 + r0 + r;
        float val = acc[m][n][r];
        if constexpr (MODE == 4) {
          if (col < 1024) {
            ((u16*)outp)[row * 1024 + col] = f2b(softplus_f(val + bias[col]));
          } else if (col < 1040) {
            ((float*)outp2)[row * 32 + col - 1024] = val + bias2[col - 1024];
          } else if (col < 1056) {
            ((float*)outp2)[row * 32 + col - 1024] = val + bias3[col - 1040];
          }
        } else if constexpr (MODE == 5) {
          if (col < 1024) {
            val += bias[col];
            ((u16*)outp)[row * 1024 + col] = f2b(val);
          } else {
            ((u16*)outp2)[row * 1024 + col - 1024] = f2b(silu_f(val + bias2[col - 1024]));
          }
        } else if constexpr (MODE == 6) {
          val += bias[col];
          ((u16*)outp)[row * ldOut + col] = f2b(val + resid[row * ldOut + col]);
        } else if constexpr (MODE == 7) {
          val += bias[col];
          ((float*)outp)[row * ldOut + col] = val + b2f(((const u16*)resid)[row * ldOut + col]);
        } else {  // MODE 2
          ((u16*)outp)[row * ldOut + col] = f2b(gelu_f(val + bias[col]));
        }
      }
    }
  }
}

// ---------------- chunked selective scan ----------------
// pass 1: local scan (h0=0): h_out/chunk + sum(dt) + y_local + inclusive cumdt (bf16)
__global__ __launch_bounds__(256)
void scan_pass1(const u16* __restrict__ xc, const u16* __restrict__ dtb,
                const float* __restrict__ bcb, const float* __restrict__ A_log,
                const float* __restrict__ D_p, float* __restrict__ hloc,
                float* __restrict__ sdt, u16* __restrict__ ylb, u16* __restrict__ cdb)
{
  const int bx = blockIdx.x;
  const int b = bx >> 9;
  const int ch = (bx >> 4) & 31;
  const int dBase = (bx & 15) * 64;
  const int t = threadIdx.x;
  const int dl = t >> 2;
  const int q = t & 3;
  const int d = dBase + dl;

  __shared__ float s_bc[32][32];
  __shared__ u16 s_dt[32][64];
  __shared__ u16 s_x[32][64];
  __shared__ u16 s_yl[32][64];
  __shared__ u16 s_cd[32][64];

  float Areg[4];
#pragma unroll
  for (int j = 0; j < 4; ++j) Areg[j] = -__expf(A_log[d * 16 + q * 4 + j]);
  const float Dp = D_p[d];
  float h[4] = {0.f, 0.f, 0.f, 0.f};
  float sAcc = 0.f;
  const long mBase = (long)b * SEQ + ch * CH;

  for (int c0 = 0; c0 < CH; c0 += 32) {
#pragma unroll
    for (int i = 0; i < 4; ++i) {
      int idx = i * 256 + t;
      int s = idx >> 5, j = idx & 31;
      s_bc[s][j] = bcb[(mBase + c0 + s) * 32 + j];
    }
#pragma unroll
    for (int i = 0; i < 8; ++i) {
      int idx = i * 256 + t;
      int s = idx >> 6, j = idx & 63;
      long m = mBase + c0 + s;
      s_dt[s][j] = dtb[m * DM + dBase + j];
      s_x[s][j] = xc[m * DM + dBase + j];
    }
    __syncthreads();
#pragma unroll 4
    for (int s = 0; s < 32; ++s) {
      const float dt = b2f(s_dt[s][dl]);
      const float xt = b2f(s_x[s][dl]);
      const float p = dt * xt;
      sAcc += dt;
      float y = 0.f;
#pragma unroll
      for (int j = 0; j < 4; ++j) {
        h[j] = __expf(dt * Areg[j]) * h[j] + p * s_bc[s][q * 4 + j];
        y = fmaf(h[j], s_bc[s][16 + q * 4 + j], y);
      }
      y += __shfl_xor(y, 1);
      y += __shfl_xor(y, 2);
      if (q == 0) s_yl[s][dl] = f2b(y + Dp * xt);
      if (q == 1) s_cd[s][dl] = f2b(sAcc);
    }
    __syncthreads();
#pragma unroll
    for (int i = 0; i < 8; ++i) {
      int idx = i * 256 + t;
      int s = idx >> 6, j = idx & 63;
      long m = mBase + c0 + s;
      ylb[m * DM + dBase + j] = s_yl[s][j];
      cdb[m * DM + dBase + j] = s_cd[s][j];
    }
    __syncthreads();
  }
  const long base = (((long)b * NCH + ch) * 1024 + d) * 16 + q * 4;
  float4 hv; hv.x = h[0]; hv.y = h[1]; hv.z = h[2]; hv.w = h[3];
  *(float4*)&hloc[base] = hv;
  if (q == 0) sdt[((long)b * NCH + ch) * 1024 + d] = sAcc;
}

// pass 2: sequential combine over chunks
__global__ __launch_bounds__(256)
void scan_pass2(const float* __restrict__ A_log, const float* __restrict__ sdt,
                const float* __restrict__ hloc, float* __restrict__ hin)
{
  const int tid = blockIdx.x * 256 + threadIdx.x;
  const int b = tid >> 14;
  const int dn = tid & 16383;
  const int d = dn >> 4;
  const float A = -__expf(A_log[dn]);
  float h = 0.f;
  for (int c = 0; c < NCH; ++c) {
    const long idx = (((long)b * NCH + c) << 14) + dn;
    hin[idx] = h;
    h = __expf(A * sdt[((long)b * NCH + c) * 1024 + d]) * h + hloc[idx];
  }
}

// pass 3 (parallel): yv = (y_local + sum_n C[t,n]*hin[n]*exp(A_n*cumdt)) * v
__global__ __launch_bounds__(256)
void scan_fix(const float* __restrict__ bcb, const u16* __restrict__ ylb,
              const u16* __restrict__ cdb, const u16* __restrict__ vg,
              const float* __restrict__ A_log, const float* __restrict__ hin,
              u16* __restrict__ yv)
{
  const int bx = blockIdx.x;
  const int b = bx >> 9;
  const int ch = (bx >> 4) & 31;
  const int dBase = (bx & 15) * 64;
  const int t = threadIdx.x;
  const int dl = t >> 2;
  const int q = t & 3;
  const int d = dBase + dl;

  __shared__ float s_c[32][16];
  __shared__ u16 s_cd[32][64];
  __shared__ u16 s_yl[32][64];
  __shared__ u16 s_v[32][64];
  __shared__ u16 s_o[32][64];

  float Areg[4];
#pragma unroll
  for (int j = 0; j < 4; ++j) Areg[j] = -__expf(A_log[d * 16 + q * 4 + j]);
  const float4 hv4 = *(const float4*)&hin[(((long)b * NCH + ch) * 1024 + d) * 16 + q * 4];
  const float hv[4] = {hv4.x, hv4.y, hv4.z, hv4.w};

  const long mBase = (long)b * SEQ + ch * CH;

  for (int c0 = 0; c0 < CH; c0 += 32) {
#pragma unroll
    for (int i = 0; i < 2; ++i) {
      int idx = i * 256 + t;
      int s = idx >> 4, j = idx & 15;
      s_c[s][j] = bcb[(mBase + c0 + s) * 32 + 16 + j];
    }
#pragma unroll
    for (int i = 0; i < 8; ++i) {
      int idx = i * 256 + t;
      int s = idx >> 6, j = idx & 63;
      long m = mBase + c0 + s;
      s_cd[s][j] = cdb[m * DM + dBase + j];
      s_yl[s][j] = ylb[m * DM + dBase + j];
      s_v[s][j] = vg[m * DM + dBase + j];
    }
    __syncthreads();
#pragma unroll 4
    for (int s = 0; s < 32; ++s) {
      const float cd = b2f(s_cd[s][dl]);
      float corr = 0.f;
#pragma unroll
      for (int j = 0; j < 4; ++j)
        corr = fmaf(s_c[s][q * 4 + j] * hv[j], __expf(Areg[j] * cd), corr);
      corr += __shfl_xor(corr, 1);
      corr += __shfl_xor(corr, 2);
      if (q == 0)
        s_o[s][dl] = f2b((b2f(s_yl[s][dl]) + corr) * b2f(s_v[s][dl]));
    }
    __syncthreads();
#pragma unroll
    for (int i = 0; i < 8; ++i) {
      int idx = i * 256 + t;
      int s = idx >> 6, j = idx & 63;
      yv[(mBase + c0 + s) * DM + dBase + j] = s_o[s][j];
    }
    __syncthreads();
  }
}

extern "C" void kernel_launch(void* const* d_in, const int* in_sizes, int n_in,
                              void* d_out, int out_size, void* d_ws, size_t ws_size,
                              hipStream_t stream)
{
  (void)in_sizes; (void)n_in; (void)out_size; (void)ws_size;
  const float* x      = (const float*)d_in[0];
  const float* ln1_g  = (const float*)d_in[1];
  const float* ln1_b  = (const float*)d_in[2];
  const float* ln_g   = (const float*)d_in[3];
  const float* ln_b   = (const float*)d_in[4];
  const float* w1_w   = (const float*)d_in[5];
  const float* w1_b   = (const float*)d_in[6];
  const float* v1_w   = (const float*)d_in[7];
  const float* v1_b   = (const float*)d_in[8];
  const float* w2_w   = (const float*)d_in[9];
  const float* w2_b   = (const float*)d_in[10];
  const float* conv_w = (const float*)d_in[11];
  const float* dt_w   = (const float*)d_in[12];
  const float* dt_b   = (const float*)d_in[13];
  const float* Bp_w   = (const float*)d_in[14];
  const float* Bp_b   = (const float*)d_in[15];
  const float* Cp_w   = (const float*)d_in[16];
  const float* Cp_b   = (const float*)d_in[17];
  const float* A_log  = (const float*)d_in[18];
  const float* D_p    = (const float*)d_in[19];
  const float* ln2_g  = (const float*)d_in[20];
  const float* ln2_b  = (const float*)d_in[21];
  const float* ff1_w  = (const float*)d_in[22];
  const float* ff1_b  = (const float*)d_in[23];
  const float* ff2_w  = (const float*)d_in[24];
  const float* ff2_b  = (const float*)d_in[25];

  char* ws = (char*)d_ws;
  size_t cur = 0;
  auto alloc = [&](size_t bytes) -> void* {
    void* p = ws + cur;
    cur = (cur + bytes + 255) & ~(size_t)255;
    return p;
  };

  u16* wv1T  = (u16*)alloc((size_t)2048 * 1024 * 2);   // [w1T ; v1T]
  u16* w2T   = (u16*)alloc((size_t)1024 * 1024 * 2);
  u16* wcatT = (u16*)alloc((size_t)1152 * 1024 * 2);
  u16* ff1T  = (u16*)alloc((size_t)3072 * 1024 * 2);
  u16* ff2T  = (u16*)alloc((size_t)1024 * 3072 * 2);
  u16* xm    = (u16*)alloc((size_t)NTOK * DM * 2);
  u16* x1b   = (u16*)alloc((size_t)NTOK * DM * 2);
  u16* vb    = (u16*)alloc((size_t)NTOK * DM * 2);     // 16 MB
  u16* xcb   = (u16*)alloc((size_t)NTOK * DM * 2);     // 16 MB (contiguous after vb)
  u16* dtb   = (u16*)alloc((size_t)NTOK * DM * 2);     // 16 MB (contiguous after xcb)
  float* bcb = (float*)alloc((size_t)NTOK * 32 * 4);   // [B|C] compact f32
  u16* x2u   = (u16*)alloc((size_t)NTOK * DM * 2);     // x2 bf16
  float* hloc = (float*)alloc((size_t)4 * NCH * 1024 * 16 * 4);  // 8 MB
  float* hin  = (float*)alloc((size_t)4 * NCH * 1024 * 16 * 4);  // 8 MB
  float* sdtb = (float*)alloc((size_t)4 * NCH * 1024 * 4);       // 512 KB
  u16* yvb  = xm;          // reuse: xm dead after fused GEMM; consumed by w2
  u16* ylb  = x1b;         // reuse: x1 dead after conv; consumed by scan_fix
  u16* xn2  = x1b;         // reuse: ylb dead before LN writes xn2
  u16* cdb  = x2u;         // reuse: consumed by scan_fix before w2 writes x2u
  u16* hb   = vb;          // reuse: vb+xcb+dtb = exactly 48 MB contiguous, all dead
                           // after scan_fix; ff1 output (8192x3072 bf16 = 48 MB)

  const dim3 tb32(32, 8);
  // weight prep
  wtrans4<<<dim3(32, 32, 4), tb32, 0, stream>>>(w1_w, v1_w, w2_w, dt_w,
                                                wv1T, wv1T + (size_t)1024 * 1024,
                                                w2T, wcatT);
  small_trans<<<64, 256, 0, stream>>>(Bp_w, Cp_w, wcatT);
  wtrans_ff<<<6144, tb32, 0, stream>>>(ff1_w, ff2_w, ff1T, ff2T);

  // LN1 -> LN2 -> xm (bf16)
  ln_ln_kernel<<<NTOK, 256, 0, stream>>>(x, ln1_g, ln1_b, ln_g, ln_b, xm);

  // fused: x1 = xm @ w1 + b ; v = silu(xm @ v1 + b)   (N=2048; 256-row tile, 8 waves)
  gemm_bt<5, 128, 1, 4><<<512, 512, 0, stream>>>(xm, wv1T, w1_b, v1_b, nullptr, nullptr,
                                                 x1b, vb, 1024, 1024, 16);

  // xc = silu(depthwise_conv(x1))
  conv_silu_kernel<<<(NTOK * DM) / (256 * 8), 256, 0, stream>>>(x1b, conv_w, xcb);

  // dt (bf16, softplus) + BC (compact f32): 256-row tile, NU=2 (80 KB LDS,
  // 2 blocks/CU = 16 waves)
  gemm_bt<4, 64, 2, 4><<<544, 512, 0, stream>>>(xcb, wcatT, dt_b, Bp_b, Cp_b, nullptr,
                                                dtb, bcb, 1024, 1024, 17);

  // chunked selective scan: local scan (+ y_local, cumdt) -> combine -> parallel fix
  scan_pass1<<<2048, 256, 0, stream>>>(xcb, dtb, bcb, A_log, D_p, hloc, sdtb, ylb, cdb);
  scan_pass2<<<256, 256, 0, stream>>>(A_log, sdtb, hloc, hin);
  scan_fix<<<2048, 256, 0, stream>>>(bcb, ylb, cdb, vb, A_log, hin, yvb);

  // x2 = yv @ w2 + b + x  (bf16 out, f32 resid; 256-row tile, NU=2)
  gemm_bt<6, 64, 2, 4><<<512, 512, 0, stream>>>(yvb, w2T, w2_b, nullptr, nullptr, x,
                                                x2u, nullptr, 1024, 1024, 16);

  // xn2 = LN(x2) (bf16 in/out)
  ln_bf_kernel<<<NTOK, 256, 0, stream>>>(x2u, ln2_g, ln2_b, xn2);

  // h = gelu(xn2 @ ff1 + b) (bf16, ld 3072; 256-row tile, 8 waves)
  gemm_bt<2, 128, 1, 4><<<768, 512, 0, stream>>>(xn2, ff1T, ff1_b, nullptr, nullptr, nullptr,
                                                 hb, nullptr, 1024, 3072, 24);

  // out = h @ ff2 + b + x2  (f32 out, bf16 resid; BK=64 pipeline)
  gemm_bt<7, 128, 2, 2><<<512, 256, 0, stream>>>(hb, ff2T, ff2_b, nullptr, nullptr,
                                                 (const float*)x2u, d_out, nullptr,
                                                 3072, 1024, 8);
}